// Round 10
// baseline (1024.993 us; speedup 1.0000x reference)
//
#include <hip/hip_runtime.h>
#include <hip/hip_bf16.h>

#define NTOK 49
#define DIMC 384
#define NH 12
#define QSCALE 0.17677669529663687f

typedef __attribute__((ext_vector_type(8))) short short8;
typedef __attribute__((ext_vector_type(4))) float f32x4;
typedef unsigned int u32;

// ws layout: wqb2 (54 tiles x 16KB swz qkv W) | wpb (18 tiles proj W) | qkvb (frag q/k/v, per chunk) | avb (proj A tiles, per chunk)
#define WQB2_SHORTS (54 * 8192)
#define WPB_SHORTS  (18 * 8192)

__device__ __forceinline__ short f2bf(float f) {
    __bf16 h = (__bf16)f;
    return __builtin_bit_cast(short, h);
}
__device__ __forceinline__ float bf2f(short s) {
    u32 u = ((u32)(unsigned short)s) << 16;
    return __builtin_bit_cast(float, u);
}
__device__ __forceinline__ int cof(int p) { return 13 * (p / 7) + (p % 7); }

__device__ __forceinline__ void gld_lds16(const void* g, void* l) {
    __builtin_amdgcn_global_load_lds(
        (const __attribute__((address_space(1))) u32*)g,
        (__attribute__((address_space(3))) u32*)l, 16, 0, 0);
}

// fallback gather (fp32 source, uncoalesced — correctness path only)
__device__ __forceinline__ short8 gather_bf(const float* __restrict__ w, int row, int k0) {
    const float* p = w + row * DIMC + k0;
    float4 a = *(const float4*)p;
    float4 b = *(const float4*)(p + 4);
    short8 r;
    r[0]=f2bf(a.x); r[1]=f2bf(a.y); r[2]=f2bf(a.z); r[3]=f2bf(a.w);
    r[4]=f2bf(b.x); r[5]=f2bf(b.y); r[6]=f2bf(b.z); r[7]=f2bf(b.w);
    return r;
}

// ---------------- prep2: swizzled 128x64 B-tiles for qkv (9 nb) + proj (3 nb) ----------------
// tile (nb,kc): row r, 16B-group g holds W[nb*128+r][kc*64 + ((g^(r&7))<<3) .. +7] as bf16
__global__ void prep2(const float* __restrict__ qw, const float* __restrict__ pw,
                      short* __restrict__ wqb2, short* __restrict__ wpb) {
    int gt = blockIdx.x * 256 + threadIdx.x;    // 73728 total
    int tile = gt >> 10;
    int rem = gt & 1023;
    int r = rem >> 3, g = rem & 7;
    int kc = tile % 6;
    int k0 = kc * 64 + ((g ^ (r & 7)) << 3);
    short8 o;
    if (tile < 54) {
        int nb = tile / 6;
        const float* src = qw + (size_t)(nb * 128 + r) * DIMC + k0;
        #pragma unroll
        for (int e = 0; e < 8; ++e) o[e] = f2bf(src[e]);
        *(short8*)(wqb2 + (size_t)tile * 8192 + r * 64 + g * 8) = o;
    } else {
        int t2 = tile - 54;
        int nb = t2 / 6;
        const float* src = pw + (size_t)(nb * 128 + r) * DIMC + k0;
        #pragma unroll
        for (int e = 0; e < 8; ++e) o[e] = f2bf(src[e]);
        *(short8*)(wpb + (size_t)t2 * 8192 + r * 64 + g * 8) = o;
    }
}

// ======= qkv_gemm: padded M-tile (=2 windows) x 128 cols, K=384; epilogue -> fragment layout =======
// qkvb frag layout per (local window wl, head): fid 0-3 q stripes, 4-7 k stripes, 8-11 v (dt*2+kst)
// frag: 512 shorts, element lane*8+e; q/k: [l15=token-in-stripe][l4*8+e=dim]; v: [l15=dim16][l4*8+e=ktok]
__global__ __launch_bounds__(256, 2)
void qkv_gemm(const float* __restrict__ x, const float* __restrict__ qkv_b,
              const short* __restrict__ wqb2, short* __restrict__ qkvb, int w0)
{
    __shared__ char LDSB[65536] __attribute__((aligned(128)));
    char* Ab = LDSB;            // [2][16384]
    char* Bb = LDSB + 32768;    // [2][16384]

    const int tid = threadIdx.x;
    const int wv = tid >> 6, lane = tid & 63;
    const int l15 = lane & 15, l4 = lane >> 4;
    const int wr = wv >> 1, wc = wv & 1;
    const int mb = blockIdx.x / 9, nb = blockIdx.x % 9;

    // A-staging mapping: thread -> (row, col-half)
    const int arow = tid >> 1, achalf = tid & 1;
    const int tokA = arow & 63;
    const bool avalid = tokA < NTOK;
    const int winA = w0 + mb * 2 + (arow >> 6);
    const float* abase = x + ((size_t)winA * NTOK + (avalid ? tokA : NTOK - 1)) * DIMC + achalf * 32;
    const char* bsrc = (const char*)(wqb2 + (size_t)(nb * 6) * 8192);

    f32x4 acc[4][4];
    #pragma unroll
    for (int mi = 0; mi < 4; ++mi)
        #pragma unroll
        for (int ni = 0; ni < 4; ++ni) acc[mi][ni] = (f32x4){0.f, 0.f, 0.f, 0.f};

    f32x4 areg[8];
    // prologue: issue A(0) regs + B(0) LDS (wave-uniform LDS base + lane*16 global — m104 rule)
    #pragma unroll
    for (int i = 0; i < 8; ++i) areg[i] = *(const f32x4*)(abase + i * 4);
    #pragma unroll
    for (int it = 0; it < 4; ++it)
        gld_lds16(bsrc + it * 4096 + wv * 1024 + lane * 16, Bb + it * 4096 + wv * 1024);

    #pragma unroll
    for (int kc = 0; kc < 6; ++kc) {
        char* Acur = Ab + (kc & 1) * 16384;
        char* Bcur = Bb + (kc & 1) * 16384;
        __builtin_amdgcn_sched_barrier(0);
        asm volatile("s_waitcnt vmcnt(0)" ::: "memory");   // A(kc) regs + B(kc) DMA done
        __builtin_amdgcn_sched_barrier(0);
        // cvt + swizzled ds_write A(kc)
        #pragma unroll
        for (int q = 0; q < 4; ++q) {
            short8 pk;
            #pragma unroll
            for (int e = 0; e < 4; ++e) {
                pk[e]     = avalid ? f2bf(areg[q * 2][e])     : (short)0;
                pk[4 + e] = avalid ? f2bf(areg[q * 2 + 1][e]) : (short)0;
            }
            *(short8*)(Acur + arow * 128 + (((achalf * 4 + q) ^ (arow & 7)) << 4)) = pk;
        }
        __builtin_amdgcn_sched_barrier(0);
        asm volatile("s_waitcnt lgkmcnt(0)" ::: "memory");
        __builtin_amdgcn_s_barrier();
        __builtin_amdgcn_sched_barrier(0);
        if (kc < 5) {
            char* Bnxt = Bb + ((kc + 1) & 1) * 16384;
            #pragma unroll
            for (int it = 0; it < 4; ++it)
                gld_lds16(bsrc + (kc + 1) * 16384 + it * 4096 + wv * 1024 + lane * 16,
                          Bnxt + it * 4096 + wv * 1024);
            #pragma unroll
            for (int i = 0; i < 8; ++i) areg[i] = *(const f32x4*)(abase + (kc + 1) * 64 + i * 4);
        }
        __builtin_amdgcn_s_setprio(1);
        #pragma unroll
        for (int ksub = 0; ksub < 2; ++ksub) {
            short8 a[4], b[4];
            #pragma unroll
            for (int mi = 0; mi < 4; ++mi) {
                int row = wr * 64 + mi * 16 + l15;
                a[mi] = *(const short8*)(Acur + row * 128 + ((ksub * 64 + l4 * 16) ^ ((row & 7) << 4)));
            }
            #pragma unroll
            for (int ni = 0; ni < 4; ++ni) {
                int row = wc * 64 + ni * 16 + l15;
                b[ni] = *(const short8*)(Bcur + row * 128 + ((ksub * 64 + l4 * 16) ^ ((row & 7) << 4)));
            }
            #pragma unroll
            for (int mi = 0; mi < 4; ++mi)
                #pragma unroll
                for (int ni = 0; ni < 4; ++ni)
                    acc[mi][ni] = __builtin_amdgcn_mfma_f32_16x16x32_bf16(
                        a[mi], b[ni], acc[mi][ni], 0, 0, 0);
        }
        __builtin_amdgcn_s_setprio(0);
    }

    __syncthreads();   // all MFMA done before slab reuse of Ab region

    // ---- epilogue: bias (+scale), per-wave LDS transpose, frag stores ----
    float bias[4];
    #pragma unroll
    for (int ni = 0; ni < 4; ++ni) bias[ni] = qkv_b[nb * 128 + wc * 64 + ni * 16 + l15];

    char* slab = LDSB + wv * 8192;   // 64 rows x 128B
    const int wl = mb * 2 + wr;      // local window
    const int sub = nb / 3;          // 0=q 1=k 2=v

    if (sub < 2) {
        #pragma unroll
        for (int mi = 0; mi < 4; ++mi)
            #pragma unroll
            for (int ni = 0; ni < 4; ++ni)
                #pragma unroll
                for (int reg = 0; reg < 4; ++reg) {
                    float v = acc[mi][ni][reg] + bias[ni];
                    if (sub == 0) v *= QSCALE;
                    int rowp = mi * 16 + l4 * 4 + reg, colp = ni * 16 + l15;
                    *(short*)(slab + rowp * 128 + ((colp * 2) ^ ((rowp & 7) << 4))) = f2bf(v);
                }
        __builtin_amdgcn_sched_barrier(0);
        asm volatile("s_waitcnt lgkmcnt(0)" ::: "memory");
        __builtin_amdgcn_sched_barrier(0);
        #pragma unroll
        for (int hh = 0; hh < 2; ++hh)
            #pragma unroll
            for (int s = 0; s < 4; ++s) {
                int head = (nb % 3) * 4 + wc * 2 + hh;
                int rowp = s * 16 + l15;
                short8 frag = *(const short8*)(slab + rowp * 128 +
                              ((hh * 64 + l4 * 16) ^ ((rowp & 7) << 4)));
                *(short8*)(qkvb + (((size_t)wl * NH + head) * 12 + sub * 4 + s) * 512 + lane * 8) = frag;
            }
    } else {
        // v: transposed slab [col][row]
        #pragma unroll
        for (int mi = 0; mi < 4; ++mi)
            #pragma unroll
            for (int ni = 0; ni < 4; ++ni)
                #pragma unroll
                for (int reg = 0; reg < 4; ++reg) {
                    float v = acc[mi][ni][reg] + bias[ni];
                    int rowp = mi * 16 + l4 * 4 + reg, colp = ni * 16 + l15;
                    *(short*)(slab + colp * 128 + ((rowp * 2) ^ ((colp & 7) << 4))) = f2bf(v);
                }
        __builtin_amdgcn_sched_barrier(0);
        asm volatile("s_waitcnt lgkmcnt(0)" ::: "memory");
        __builtin_amdgcn_sched_barrier(0);
        #pragma unroll
        for (int hh = 0; hh < 2; ++hh)
            #pragma unroll
            for (int dt = 0; dt < 2; ++dt)
                #pragma unroll
                for (int kst = 0; kst < 2; ++kst) {
                    int head = (nb - 6) * 4 + wc * 2 + hh;
                    int row2 = hh * 32 + dt * 16 + l15;
                    short8 frag = *(const short8*)(slab + row2 * 128 +
                                  ((kst * 64 + l4 * 16) ^ ((row2 & 7) << 4)));
                    *(short8*)(qkvb + (((size_t)wl * NH + head) * 12 + 8 + dt * 2 + kst) * 512 + lane * 8) = frag;
                }
    }
}

// ======= attn_win: 1 block = 1 window, 4 waves = 4 q-stripes, zero barriers in head loop =======
__global__ __launch_bounds__(256)
void attn_win(const float* __restrict__ mask, const float* __restrict__ bias_table,
              const short* __restrict__ qkvb, char* __restrict__ avb, int w0)
{
    __shared__ short SA[6144] __attribute__((aligned(128)));   // PS 4x1024 | BT 2048
    const int PS2 = 0, BT2 = 4096;

    const int tid = threadIdx.x;
    const int wv = tid >> 6, lane = tid & 63;
    const int l15 = lane & 15, l4 = lane >> 4;
    const int wl = blockIdx.x;
    const int win = w0 + wl;

    for (int i = tid; i < 169 * NH; i += 256) SA[BT2 + i] = f2bf(bias_table[i]);

    // mask packed bf16 pairs with col-pad folded + rel-idx
    u32 mvp[4][2];
    int bidx[4][4];
    {
        const float* maskp = mask + (size_t)(win & 63) * (NTOK * NTOK);
        #pragma unroll
        for (int t = 0; t < 4; ++t) {
            int m = t * 16 + l15;
            float pad = (m < NTOK) ? 0.f : -1e30f;
            #pragma unroll
            for (int rp = 0; rp < 2; ++rp) {
                float v[2];
                #pragma unroll
                for (int e = 0; e < 2; ++e) {
                    int i = wv * 16 + l4 * 4 + rp * 2 + e;
                    v[e] = ((i < NTOK && m < NTOK) ? maskp[i * NTOK + m] : 0.f) + pad;
                }
                mvp[t][rp] = (u32)(unsigned short)f2bf(v[0]) |
                             ((u32)(unsigned short)f2bf(v[1]) << 16);
            }
        }
        int cofi[4], cofm[4];
        #pragma unroll
        for (int t = 0; t < 4; ++t) {
            int m = t * 16 + l15;
            cofm[t] = cof(48 - (m < NTOK ? m : 48));
        }
        #pragma unroll
        for (int reg = 0; reg < 4; ++reg) {
            int i = wv * 16 + l4 * 4 + reg;
            cofi[reg] = cof(i < NTOK ? i : 48);
        }
        #pragma unroll
        for (int t = 0; t < 4; ++t)
            #pragma unroll
            for (int reg = 0; reg < 4; ++reg)
                bidx[t][reg] = (cofi[reg] + cofm[t]) * NH;
    }
    const f32x4 zf = (f32x4){0.f, 0.f, 0.f, 0.f};
    __syncthreads();   // BT visible

    const short* qh = qkvb + (size_t)wl * (NH * 12 * 512);

    #pragma unroll 1
    for (int h = 0; h < NH; ++h) {
        const short* hb = qh + h * (12 * 512) + lane * 8;
        short8 q = *(const short8*)(hb + 0 * 512 + wv * 512);
        short8 kf[4], vf[4];
        #pragma unroll
        for (int t = 0; t < 4; ++t) kf[t] = *(const short8*)(hb + (4 + t) * 512);
        #pragma unroll
        for (int j = 0; j < 4; ++j) vf[j] = *(const short8*)(hb + (8 + j) * 512);

        f32x4 sc[4];
        #pragma unroll
        for (int t = 0; t < 4; ++t)
            sc[t] = __builtin_amdgcn_mfma_f32_16x16x32_bf16(q, kf[t], zf, 0, 0, 0);

        float p[4][4];
        #pragma unroll
        for (int t = 0; t < 4; ++t)
            #pragma unroll
            for (int reg = 0; reg < 4; ++reg) {
                u32 pk = mvp[t][reg >> 1];
                float mval = bf2f((short)((reg & 1) ? (pk >> 16) : (pk & 0xffff)));
                float bt = bf2f(SA[BT2 + bidx[t][reg] + h]);
                p[t][reg] = sc[t][reg] + mval + bt;
            }
        #pragma unroll
        for (int reg = 0; reg < 4; ++reg) {
            float mx = fmaxf(fmaxf(p[0][reg], p[1][reg]), fmaxf(p[2][reg], p[3][reg]));
            #pragma unroll
            for (int off = 8; off >= 1; off >>= 1) mx = fmaxf(mx, __shfl_xor(mx, off, 64));
            float s0 = 0.f;
            #pragma unroll
            for (int t = 0; t < 4; ++t) { p[t][reg] = __expf(p[t][reg] - mx); s0 += p[t][reg]; }
            #pragma unroll
            for (int off = 8; off >= 1; off >>= 1) s0 += __shfl_xor(s0, off, 64);
            float rs = 1.f / s0;
            #pragma unroll
            for (int t = 0; t < 4; ++t) p[t][reg] *= rs;
        }
        // P -> per-wave PS slab (swizzled 128B rows)
        #pragma unroll
        for (int t = 0; t < 4; ++t)
            #pragma unroll
            for (int reg = 0; reg < 4; ++reg) {
                int r = l4 * 4 + reg;
                int byt = r * 128 + ((((t * 16 + l15) << 1)) ^ ((r & 7) << 4));
                SA[PS2 + wv * 1024 + (byt >> 1)] = f2bf(p[t][reg]);
            }
        // PV (pa from LDS transpose, bv from registers)
        f32x4 av[2];
        av[0] = zf; av[1] = zf;
        #pragma unroll
        for (int kst = 0; kst < 2; ++kst) {
            short8 pa;
            {
                int byt = l15 * 128 + (((kst * 64 + l4 * 16)) ^ ((l15 & 7) << 4));
                pa = *(const short8*)&SA[PS2 + wv * 1024 + (byt >> 1)];
            }
            #pragma unroll
            for (int dt = 0; dt < 2; ++dt)
                av[dt] = __builtin_amdgcn_mfma_f32_16x16x32_bf16(pa, vf[dt * 2 + kst], av[dt], 0, 0, 0);
        }
        // AV -> avb (padded proj-A tile layout, swizzled)
        #pragma unroll
        for (int dt = 0; dt < 2; ++dt)
            #pragma unroll
            for (int reg = 0; reg < 4; ++reg) {
                int tok = wv * 16 + l4 * 4 + reg;
                if (tok < NTOK) {
                    int r = (wl & 1) * 64 + tok;
                    int inner = ((((h & 1) << 6) | ((dt * 16 + l15) << 1))) ^ ((r & 7) << 4);
                    *(short*)(avb + (size_t)((wl >> 1) * 6 + (h >> 1)) * 16384 + r * 128 + inner)
                        = f2bf(av[dt][reg]);
                }
            }
    }
}

// ======= proj_pad: out = AV @ projW^T + b, padded M tiles (2 windows/tile) =======
__global__ __launch_bounds__(256, 2)
void proj_pad(const char* __restrict__ avb, const short* __restrict__ wpb,
              const float* __restrict__ proj_b, float* __restrict__ out, int mb0)
{
    __shared__ char LC[2][32768] __attribute__((aligned(128)));

    const int tid = threadIdx.x;
    const int wv = tid >> 6, lane = tid & 63;
    const int l15 = lane & 15, l4 = lane >> 4;
    const int wr = wv >> 1, wc = wv & 1;
    const int mb = blockIdx.x / 3, nb = blockIdx.x % 3;

    const char* asrc = avb + (size_t)mb * 6 * 16384;
    const char* bsrc = (const char*)wpb + (size_t)nb * 6 * 16384;

    f32x4 acc[4][4];
    #pragma unroll
    for (int mi = 0; mi < 4; ++mi)
        #pragma unroll
        for (int ni = 0; ni < 4; ++ni) acc[mi][ni] = (f32x4){0.f, 0.f, 0.f, 0.f};

    #pragma unroll
    for (int it = 0; it < 4; ++it) {
        int L = (wv * 4 + it) * 1024;
        gld_lds16(asrc + L + lane * 16, &LC[0][L]);
        gld_lds16(bsrc + L + lane * 16, &LC[0][16384 + L]);
    }

    #pragma unroll
    for (int kc = 0; kc < 6; ++kc) {
        __builtin_amdgcn_sched_barrier(0);
        asm volatile("s_waitcnt vmcnt(0)" ::: "memory");
        __builtin_amdgcn_s_barrier();
        __builtin_amdgcn_sched_barrier(0);
        if (kc < 5) {
            #pragma unroll
            for (int it = 0; it < 4; ++it) {
                int L = (wv * 4 + it) * 1024;
                gld_lds16(asrc + (kc + 1) * 16384 + L + lane * 16, &LC[(kc + 1) & 1][L]);
                gld_lds16(bsrc + (kc + 1) * 16384 + L + lane * 16, &LC[(kc + 1) & 1][16384 + L]);
            }
        }
        const char* bufp = LC[kc & 1];
        __builtin_amdgcn_s_setprio(1);
        #pragma unroll
        for (int ksub = 0; ksub < 2; ++ksub) {
            short8 a[4], b[4];
            #pragma unroll
            for (int mi = 0; mi < 4; ++mi) {
                int row = wr * 64 + mi * 16 + l15;
                a[mi] = *(const short8*)(bufp + row * 128 +
                        ((ksub * 64 + l4 * 16) ^ ((row & 7) << 4)));
            }
            #pragma unroll
            for (int ni = 0; ni < 4; ++ni) {
                int row = wc * 64 + ni * 16 + l15;
                b[ni] = *(const short8*)(bufp + 16384 + row * 128 +
                        ((ksub * 64 + l4 * 16) ^ ((row & 7) << 4)));
            }
            #pragma unroll
            for (int mi = 0; mi < 4; ++mi)
                #pragma unroll
                for (int ni = 0; ni < 4; ++ni)
                    acc[mi][ni] = __builtin_amdgcn_mfma_f32_16x16x32_bf16(
                        a[mi], b[ni], acc[mi][ni], 0, 0, 0);
        }
        __builtin_amdgcn_s_setprio(0);
    }

    float pb[4];
    #pragma unroll
    for (int ni = 0; ni < 4; ++ni) pb[ni] = proj_b[nb * 128 + wc * 64 + ni * 16 + l15];
    const int wg = (mb0 + mb) * 2 + wr;   // global window
    #pragma unroll
    for (int mi = 0; mi < 4; ++mi) {
        #pragma unroll
        for (int ni = 0; ni < 4; ++ni) {
            #pragma unroll
            for (int reg = 0; reg < 4; ++reg) {
                int tok = mi * 16 + l4 * 4 + reg;
                if (tok < NTOK)
                    out[((size_t)wg * NTOK + tok) * DIMC + nb * 128 + wc * 64 + ni * 16 + l15]
                        = acc[mi][ni][reg] + pb[ni];
            }
        }
    }
}

// ================= fallback: monolithic gather kernel (no ws) =================
__global__ __launch_bounds__(256, 2)
void winattn_fallback(const float* __restrict__ x, const float* __restrict__ mask,
                      const float* __restrict__ qkv_w, const float* __restrict__ qkv_b,
                      const float* __restrict__ proj_w, const float* __restrict__ proj_b,
                      const float* __restrict__ bias_table, float* __restrict__ out)
{
    __shared__ short SL[26624] __attribute__((aligned(128)));
    const int tid = threadIdx.x, wv = tid >> 6, lane = tid & 63;
    const int l15 = lane & 15, l4 = lane >> 4;
    const int win = blockIdx.x;
    const int xbase = win * (NTOK * DIMC);
    const int KSo = 0, VTo = 2048, PSo = 4096, QAo = 8192;

    short8 xf[12];
    {
        const int row = wv * 16 + l15;
        const bool valid = row < NTOK;
        const float* xr = x + xbase + row * DIMC;
        #pragma unroll
        for (int ks = 0; ks < 12; ++ks)
            xf[ks] = valid ? gather_bf(xr, 0, ks * 32 + l4 * 8) : (short8)0;
    }
    float mv[4][4]; int bidx[4][4]; float negm[4];
    {
        const float* maskp = mask + (win & 63) * (NTOK * NTOK);
        int cofi[4], cofm[4];
        #pragma unroll
        for (int t = 0; t < 4; ++t) {
            int m = t * 16 + l15;
            negm[t] = (m < NTOK) ? 0.f : -1e30f;
            cofm[t] = cof(48 - (m < NTOK ? m : 48));
            #pragma unroll
            for (int reg = 0; reg < 4; ++reg) {
                int i = wv * 16 + l4 * 4 + reg;
                mv[t][reg] = (i < NTOK && m < NTOK) ? maskp[i * NTOK + m] : 0.f;
            }
        }
        #pragma unroll
        for (int reg = 0; reg < 4; ++reg) {
            int i = wv * 16 + l4 * 4 + reg;
            cofi[reg] = cof(i < NTOK ? i : 48);
        }
        #pragma unroll
        for (int t = 0; t < 4; ++t)
            #pragma unroll
            for (int reg = 0; reg < 4; ++reg) bidx[t][reg] = (cofi[reg] + cofm[t]) * NH;
    }
    f32x4 pacc[24];
    #pragma unroll
    for (int t = 0; t < 24; ++t) pacc[t] = (f32x4){0.f, 0.f, 0.f, 0.f};
    const f32x4 zf = (f32x4){0.f, 0.f, 0.f, 0.f};
    __syncthreads();

    #pragma unroll 1
    for (int h = 0; h < NH; ++h) {
        f32x4 qa[6];
        #pragma unroll
        for (int nt = 0; nt < 6; ++nt) qa[nt] = zf;
        #pragma unroll
        for (int nt = 0; nt < 6; ++nt) {
            const int grow = (nt >> 1) * DIMC + h * 32 + (nt & 1) * 16 + l15;
            #pragma unroll
            for (int ks = 0; ks < 12; ++ks) {
                short8 b = gather_bf(qkv_w, grow, ks * 32 + l4 * 8);
                qa[nt] = __builtin_amdgcn_mfma_f32_16x16x32_bf16(xf[ks], b, qa[nt], 0, 0, 0);
            }
        }
        #pragma unroll
        for (int nt = 0; nt < 6; ++nt) {
            const int sub = nt >> 1;
            const int colw = (nt & 1) * 16 + l15;
            const float bias = qkv_b[sub * DIMC + h * 32 + colw];
            #pragma unroll
            for (int reg = 0; reg < 4; ++reg) {
                const int tokg = wv * 16 + l4 * 4 + reg;
                float val = qa[nt][reg] + bias;
                if (sub == 0) {
                    int byt = tokg * 64 + ((colw << 1) ^ ((tokg & 3) << 4));
                    SL[QAo + (byt >> 1)] = f2bf(val * QSCALE);
                } else if (sub == 1) {
                    int byt = tokg * 64 + ((colw << 1) ^ ((tokg & 3) << 4));
                    SL[KSo + (byt >> 1)] = f2bf(val);
                } else {
                    int byt = colw * 128 + ((tokg << 1) ^ ((colw & 7) << 4));
                    SL[VTo + (byt >> 1)] = f2bf(val);
                }
            }
        }
        __syncthreads();
        short8 aq;
        { int row = wv*16+l15; int byt = row*64 + ((l4*16) ^ ((row&3)<<4));
          aq = *(const short8*)&SL[QAo + (byt>>1)]; }
        f32x4 sc[4];
        #pragma unroll
        for (int t = 0; t < 4; ++t) {
            int row = t*16+l15; int byt = row*64 + ((l4*16) ^ ((row&3)<<4));
            short8 bk = *(const short8*)&SL[KSo + (byt>>1)];
            sc[t] = __builtin_amdgcn_mfma_f32_16x16x32_bf16(aq, bk, zf, 0, 0, 0);
        }
        float p[4][4];
        #pragma unroll
        for (int t = 0; t < 4; ++t)
            #pragma unroll
            for (int reg = 0; reg < 4; ++reg)
                p[t][reg] = sc[t][reg] + mv[t][reg] + bias_table[bidx[t][reg] + h] + negm[t];
        #pragma unroll
        for (int reg = 0; reg < 4; ++reg) {
            float mx = fmaxf(fmaxf(p[0][reg], p[1][reg]), fmaxf(p[2][reg], p[3][reg]));
            #pragma unroll
            for (int off = 8; off >= 1; off >>= 1) mx = fmaxf(mx, __shfl_xor(mx, off, 64));
            float s0 = 0.f;
            #pragma unroll
            for (int t = 0; t < 4; ++t) { p[t][reg] = __expf(p[t][reg] - mx); s0 += p[t][reg]; }
            #pragma unroll
            for (int off = 8; off >= 1; off >>= 1) s0 += __shfl_xor(s0, off, 64);
            float rs = 1.f / s0;
            #pragma unroll
            for (int t = 0; t < 4; ++t) p[t][reg] *= rs;
        }
        #pragma unroll
        for (int t = 0; t < 4; ++t)
            #pragma unroll
            for (int reg = 0; reg < 4; ++reg) {
                int row = wv*16 + l4*4 + reg;
                int byt = row*128 + (((t*16+l15) << 1) ^ ((row&7)<<4));
                SL[PSo + (byt>>1)] = f2bf(p[t][reg]);
            }
        f32x4 av[2]; av[0] = zf; av[1] = zf;
        #pragma unroll
        for (int kst = 0; kst < 2; ++kst) {
            short8 pa;
            { int row = wv*16+l15; int byt = row*128 + ((kst*64+l4*16) ^ ((row&7)<<4));
              pa = *(const short8*)&SL[PSo + (byt>>1)]; }
            #pragma unroll
            for (int dt = 0; dt < 2; ++dt) {
                int d = dt*16+l15; int byt = d*128 + ((kst*64+l4*16) ^ ((d&7)<<4));
                short8 bv = *(const short8*)&SL[VTo + (byt>>1)];
                av[dt] = __builtin_amdgcn_mfma_f32_16x16x32_bf16(pa, bv, av[dt], 0, 0, 0);
            }
        }
        __syncthreads();
        #pragma unroll
        for (int dt = 0; dt < 2; ++dt)
            #pragma unroll
            for (int reg = 0; reg < 4; ++reg) {
                int row = wv*16 + l4*4 + reg;
                int byt = row*64 + (((dt*16+l15) << 1) ^ ((row&3)<<4));
                SL[QAo + (byt>>1)] = f2bf(av[dt][reg]);
            }
        __syncthreads();
        short8 aa;
        { int row = wv*16+l15; int byt = row*64 + ((l4*16) ^ ((row&3)<<4));
          aa = *(const short8*)&SL[QAo + (byt>>1)]; }
        #pragma unroll
        for (int nt = 0; nt < 24; ++nt) {
            short8 bp = gather_bf(proj_w, nt * 16 + l15, h * 32 + l4 * 8);
            pacc[nt] = __builtin_amdgcn_mfma_f32_16x16x32_bf16(aa, bp, pacc[nt], 0, 0, 0);
        }
    }
    {
        float* op = out + xbase;
        #pragma unroll
        for (int nt = 0; nt < 24; ++nt) {
            const float pb = proj_b[nt * 16 + l15];
            #pragma unroll
            for (int reg = 0; reg < 4; ++reg) {
                const int i = wv * 16 + l4 * 4 + reg;
                if (i < NTOK) op[i * DIMC + nt * 16 + l15] = pacc[nt][reg] + pb;
            }
        }
    }
}

extern "C" void kernel_launch(void* const* d_in, const int* in_sizes, int n_in,
                              void* d_out, int out_size, void* d_ws, size_t ws_size,
                              hipStream_t stream) {
    const float* x          = (const float*)d_in[0];
    const float* mask       = (const float*)d_in[1];
    const float* qkv_w      = (const float*)d_in[2];
    const float* qkv_b      = (const float*)d_in[3];
    const float* proj_w     = (const float*)d_in[4];
    const float* proj_b     = (const float*)d_in[5];
    const float* bias_table = (const float*)d_in[6];
    float* out = (float*)d_out;

    const size_t fixed = ((size_t)WQB2_SHORTS + WPB_SHORTS) * 2;
    auto need = [&](int c) {
        size_t wpc = 4096 / c;
        return fixed + wpc * 147456UL /*qkvb*/ + wpc * 49152UL /*avb*/;
    };
    int c = 0;
    if (ws_size >= need(4)) c = 4;
    else if (ws_size >= need(8)) c = 8;

    if (c) {
        short* wqb2 = (short*)d_ws;
        short* wpb  = wqb2 + WQB2_SHORTS;
        short* qkvb = wpb + WPB_SHORTS;
        const int wpc = 4096 / c;
        char* avb = (char*)(qkvb + (size_t)wpc * 73728);

        prep2<<<288, 256, 0, stream>>>(qkv_w, proj_w, wqb2, wpb);
        for (int ch = 0; ch < c; ++ch) {
            const int w0 = ch * wpc;
            const int mbc = wpc / 2;
            qkv_gemm<<<mbc * 9, 256, 0, stream>>>(x, qkv_b, wqb2, qkvb, w0);
            attn_win<<<wpc, 256, 0, stream>>>(mask, bias_table, qkvb, avb, w0);
            proj_pad<<<mbc * 3, 256, 0, stream>>>(avb, wpb, proj_b, out, ch * mbc);
        }
    } else {
        winattn_fallback<<<4096, 256, 0, stream>>>(x, mask, qkv_w, qkv_b, proj_w,
                                                   proj_b, bias_table, out);
    }
}

// Round 11
// 809.196 us; speedup vs baseline: 1.2667x; 1.2667x over previous
//
#include <hip/hip_runtime.h>
#include <hip/hip_bf16.h>

#define NTOK 49
#define DIMC 384
#define NH 12
#define QSCALE 0.17677669529663687f

typedef __attribute__((ext_vector_type(8))) short short8;
typedef __attribute__((ext_vector_type(4))) float f32x4;
typedef unsigned int u32;

#define WQB2_SHORTS (54 * 8192)
#define WPB_SHORTS  (18 * 8192)

__device__ __forceinline__ short f2bf(float f) {
    __bf16 h = (__bf16)f;
    return __builtin_bit_cast(short, h);
}
__device__ __forceinline__ float bf2f(short s) {
    u32 u = ((u32)(unsigned short)s) << 16;
    return __builtin_bit_cast(float, u);
}
__device__ __forceinline__ int cof(int p) { return 13 * (p / 7) + (p % 7); }

__device__ __forceinline__ void gld_lds16(const void* g, void* l) {
    __builtin_amdgcn_global_load_lds(
        (const __attribute__((address_space(1))) u32*)g,
        (__attribute__((address_space(3))) u32*)l, 16, 0, 0);
}

__device__ __forceinline__ short8 gather_bf(const float* __restrict__ w, int row, int k0) {
    const float* p = w + row * DIMC + k0;
    float4 a = *(const float4*)p;
    float4 b = *(const float4*)(p + 4);
    short8 r;
    r[0]=f2bf(a.x); r[1]=f2bf(a.y); r[2]=f2bf(a.z); r[3]=f2bf(a.w);
    r[4]=f2bf(b.x); r[5]=f2bf(b.y); r[6]=f2bf(b.z); r[7]=f2bf(b.w);
    return r;
}

// ---------------- prep2: swizzled 128x64 B-tiles for qkv (9 nb) + proj (3 nb) ----------------
__global__ void prep2(const float* __restrict__ qw, const float* __restrict__ pw,
                      short* __restrict__ wqb2, short* __restrict__ wpb) {
    int gt = blockIdx.x * 256 + threadIdx.x;    // 73728 total
    int tile = gt >> 10;
    int rem = gt & 1023;
    int r = rem >> 3, g = rem & 7;
    int kc = tile % 6;
    int k0 = kc * 64 + ((g ^ (r & 7)) << 3);
    short8 o;
    if (tile < 54) {
        int nb = tile / 6;
        const float* src = qw + (size_t)(nb * 128 + r) * DIMC + k0;
        #pragma unroll
        for (int e = 0; e < 8; ++e) o[e] = f2bf(src[e]);
        *(short8*)(wqb2 + (size_t)tile * 8192 + r * 64 + g * 8) = o;
    } else {
        int t2 = tile - 54;
        int nb = t2 / 6;
        const float* src = pw + (size_t)(nb * 128 + r) * DIMC + k0;
        #pragma unroll
        for (int e = 0; e < 8; ++e) o[e] = f2bf(src[e]);
        *(short8*)(wpb + (size_t)t2 * 8192 + r * 64 + g * 8) = o;
    }
}

// ---------------- prep_x: x -> bf16 pre-swizzled padded A-tiles (per chunk) ----------------
// tile (mt,kc): row r, group g holds x[win(r)][tok(r)][kc*64 + ((g^(r&7))<<3)..+7], zero-padded tok>=49
__global__ __launch_bounds__(1024)
void prep_x(const float* __restrict__ x, short* __restrict__ xa, int w0) {
    const int bid = blockIdx.x;
    const int mt = bid / 6, kc = bid % 6;
    const int tid = threadIdx.x;
    const int r = tid >> 3, g = tid & 7;
    const int win = w0 + mt * 2 + (r >> 6);
    const int tok = r & 63;
    const int k0 = kc * 64 + ((g ^ (r & 7)) << 3);
    short8 o;
    if (tok < NTOK) {
        const float* src = x + ((size_t)win * NTOK + tok) * DIMC + k0;
        float4 a = *(const float4*)src;
        float4 b = *(const float4*)(src + 4);
        o[0]=f2bf(a.x); o[1]=f2bf(a.y); o[2]=f2bf(a.z); o[3]=f2bf(a.w);
        o[4]=f2bf(b.x); o[5]=f2bf(b.y); o[6]=f2bf(b.z); o[7]=f2bf(b.w);
    } else {
        o = (short8)0;
    }
    *(short8*)(xa + ((size_t)mt * 6 + kc) * 8192 + r * 64 + g * 8) = o;
}

// ======= qkv_gemm: proj_pad-pattern pipeline (A from xa, B from wqb2), frag-layout epilogue =======
// XCD-grouped bids: supergroup of 72 = 8 mb x 9 nb so A-tile sharers land on one XCD's L2.
__global__ __launch_bounds__(256, 2)
void qkv_gemm(const short* __restrict__ xa, const float* __restrict__ qkv_b,
              const short* __restrict__ wqb2, short* __restrict__ qkvb)
{
    __shared__ char LC[2][32768] __attribute__((aligned(128)));

    const int tid = threadIdx.x;
    const int wv = tid >> 6, lane = tid & 63;
    const int l15 = lane & 15, l4 = lane >> 4;
    const int wr = wv >> 1, wc = wv & 1;
    const int sg = blockIdx.x / 72, bb = blockIdx.x % 72;
    const int mb = sg * 8 + (bb & 7), nb = bb >> 3;

    const char* asrc = (const char*)xa + (size_t)mb * 6 * 16384;
    const char* bsrc = (const char*)wqb2 + (size_t)(nb * 6) * 8192 * 2;

    f32x4 acc[4][4];
    #pragma unroll
    for (int mi = 0; mi < 4; ++mi)
        #pragma unroll
        for (int ni = 0; ni < 4; ++ni) acc[mi][ni] = (f32x4){0.f, 0.f, 0.f, 0.f};

    #pragma unroll
    for (int it = 0; it < 4; ++it) {
        int L = (wv * 4 + it) * 1024;
        gld_lds16(asrc + L + lane * 16, &LC[0][L]);
        gld_lds16(bsrc + L + lane * 16, &LC[0][16384 + L]);
    }

    #pragma unroll
    for (int kc = 0; kc < 6; ++kc) {
        __builtin_amdgcn_sched_barrier(0);
        asm volatile("s_waitcnt vmcnt(0)" ::: "memory");
        __builtin_amdgcn_s_barrier();
        __builtin_amdgcn_sched_barrier(0);
        if (kc < 5) {
            #pragma unroll
            for (int it = 0; it < 4; ++it) {
                int L = (wv * 4 + it) * 1024;
                gld_lds16(asrc + (kc + 1) * 16384 + L + lane * 16, &LC[(kc + 1) & 1][L]);
                gld_lds16(bsrc + (kc + 1) * 16384 + L + lane * 16, &LC[(kc + 1) & 1][16384 + L]);
            }
        }
        const char* bufp = LC[kc & 1];
        __builtin_amdgcn_s_setprio(1);
        #pragma unroll
        for (int ksub = 0; ksub < 2; ++ksub) {
            short8 a[4], b[4];
            #pragma unroll
            for (int mi = 0; mi < 4; ++mi) {
                int row = wr * 64 + mi * 16 + l15;
                a[mi] = *(const short8*)(bufp + row * 128 +
                        ((ksub * 64 + l4 * 16) ^ ((row & 7) << 4)));
            }
            #pragma unroll
            for (int ni = 0; ni < 4; ++ni) {
                int row = wc * 64 + ni * 16 + l15;
                b[ni] = *(const short8*)(bufp + 16384 + row * 128 +
                        ((ksub * 64 + l4 * 16) ^ ((row & 7) << 4)));
            }
            #pragma unroll
            for (int mi = 0; mi < 4; ++mi)
                #pragma unroll
                for (int ni = 0; ni < 4; ++ni)
                    acc[mi][ni] = __builtin_amdgcn_mfma_f32_16x16x32_bf16(
                        a[mi], b[ni], acc[mi][ni], 0, 0, 0);
        }
        __builtin_amdgcn_s_setprio(0);
    }

    __syncthreads();   // all phases done before LC reuse as transpose slabs

    // ---- epilogue: bias (+scale), per-wave LDS transpose, frag stores (round-10-verified) ----
    float bias[4];
    #pragma unroll
    for (int ni = 0; ni < 4; ++ni) bias[ni] = qkv_b[nb * 128 + wc * 64 + ni * 16 + l15];

    char* slab = (char*)LC + wv * 8192;   // 64 rows x 128B, wave-private
    const int wl = mb * 2 + wr;           // local window
    const int sub = nb / 3;               // 0=q 1=k 2=v

    if (sub < 2) {
        #pragma unroll
        for (int mi = 0; mi < 4; ++mi)
            #pragma unroll
            for (int ni = 0; ni < 4; ++ni)
                #pragma unroll
                for (int reg = 0; reg < 4; ++reg) {
                    float v = acc[mi][ni][reg] + bias[ni];
                    if (sub == 0) v *= QSCALE;
                    int rowp = mi * 16 + l4 * 4 + reg, colp = ni * 16 + l15;
                    *(short*)(slab + rowp * 128 + ((colp * 2) ^ ((rowp & 7) << 4))) = f2bf(v);
                }
        __builtin_amdgcn_sched_barrier(0);
        asm volatile("s_waitcnt lgkmcnt(0)" ::: "memory");
        __builtin_amdgcn_sched_barrier(0);
        #pragma unroll
        for (int hh = 0; hh < 2; ++hh)
            #pragma unroll
            for (int s = 0; s < 4; ++s) {
                int head = (nb % 3) * 4 + wc * 2 + hh;
                int rowp = s * 16 + l15;
                short8 frag = *(const short8*)(slab + rowp * 128 +
                              ((hh * 64 + l4 * 16) ^ ((rowp & 7) << 4)));
                *(short8*)(qkvb + (((size_t)wl * NH + head) * 12 + sub * 4 + s) * 512 + lane * 8) = frag;
            }
    } else {
        #pragma unroll
        for (int mi = 0; mi < 4; ++mi)
            #pragma unroll
            for (int ni = 0; ni < 4; ++ni)
                #pragma unroll
                for (int reg = 0; reg < 4; ++reg) {
                    float v = acc[mi][ni][reg] + bias[ni];
                    int rowp = mi * 16 + l4 * 4 + reg, colp = ni * 16 + l15;
                    *(short*)(slab + colp * 128 + ((rowp * 2) ^ ((colp & 7) << 4))) = f2bf(v);
                }
        __builtin_amdgcn_sched_barrier(0);
        asm volatile("s_waitcnt lgkmcnt(0)" ::: "memory");
        __builtin_amdgcn_sched_barrier(0);
        #pragma unroll
        for (int hh = 0; hh < 2; ++hh)
            #pragma unroll
            for (int dt = 0; dt < 2; ++dt)
                #pragma unroll
                for (int kst = 0; kst < 2; ++kst) {
                    int head = (nb - 6) * 4 + wc * 2 + hh;
                    int row2 = hh * 32 + dt * 16 + l15;
                    short8 frag = *(const short8*)(slab + row2 * 128 +
                                  ((kst * 64 + l4 * 16) ^ ((row2 & 7) << 4)));
                    *(short8*)(qkvb + (((size_t)wl * NH + head) * 12 + 8 + dt * 2 + kst) * 512 + lane * 8) = frag;
                }
    }
}

// ======= attn_win: 1 block = 1 window, 4 waves = 4 q-stripes, zero barriers in head loop =======
__global__ __launch_bounds__(256)
void attn_win(const float* __restrict__ mask, const float* __restrict__ bias_table,
              const short* __restrict__ qkvb, char* __restrict__ avb, int w0)
{
    __shared__ short SA[6144] __attribute__((aligned(128)));   // PS 4x1024 | BT 2048
    const int PS2 = 0, BT2 = 4096;

    const int tid = threadIdx.x;
    const int wv = tid >> 6, lane = tid & 63;
    const int l15 = lane & 15, l4 = lane >> 4;
    const int wl = blockIdx.x;
    const int win = w0 + wl;

    for (int i = tid; i < 169 * NH; i += 256) SA[BT2 + i] = f2bf(bias_table[i]);

    u32 mvp[4][2];
    int bidx[4][4];
    {
        const float* maskp = mask + (size_t)(win & 63) * (NTOK * NTOK);
        #pragma unroll
        for (int t = 0; t < 4; ++t) {
            int m = t * 16 + l15;
            float pad = (m < NTOK) ? 0.f : -1e30f;
            #pragma unroll
            for (int rp = 0; rp < 2; ++rp) {
                float v[2];
                #pragma unroll
                for (int e = 0; e < 2; ++e) {
                    int i = wv * 16 + l4 * 4 + rp * 2 + e;
                    v[e] = ((i < NTOK && m < NTOK) ? maskp[i * NTOK + m] : 0.f) + pad;
                }
                mvp[t][rp] = (u32)(unsigned short)f2bf(v[0]) |
                             ((u32)(unsigned short)f2bf(v[1]) << 16);
            }
        }
        int cofi[4], cofm[4];
        #pragma unroll
        for (int t = 0; t < 4; ++t) {
            int m = t * 16 + l15;
            cofm[t] = cof(48 - (m < NTOK ? m : 48));
        }
        #pragma unroll
        for (int reg = 0; reg < 4; ++reg) {
            int i = wv * 16 + l4 * 4 + reg;
            cofi[reg] = cof(i < NTOK ? i : 48);
        }
        #pragma unroll
        for (int t = 0; t < 4; ++t)
            #pragma unroll
            for (int reg = 0; reg < 4; ++reg)
                bidx[t][reg] = (cofi[reg] + cofm[t]) * NH;
    }
    const f32x4 zf = (f32x4){0.f, 0.f, 0.f, 0.f};
    __syncthreads();   // BT visible

    const short* qh = qkvb + (size_t)wl * (NH * 12 * 512);

    #pragma unroll 1
    for (int h = 0; h < NH; ++h) {
        const short* hb = qh + h * (12 * 512) + lane * 8;
        short8 q = *(const short8*)(hb + 0 * 512 + wv * 512);
        short8 kf[4], vf[4];
        #pragma unroll
        for (int t = 0; t < 4; ++t) kf[t] = *(const short8*)(hb + (4 + t) * 512);
        #pragma unroll
        for (int j = 0; j < 4; ++j) vf[j] = *(const short8*)(hb + (8 + j) * 512);

        f32x4 sc[4];
        #pragma unroll
        for (int t = 0; t < 4; ++t)
            sc[t] = __builtin_amdgcn_mfma_f32_16x16x32_bf16(q, kf[t], zf, 0, 0, 0);

        float p[4][4];
        #pragma unroll
        for (int t = 0; t < 4; ++t)
            #pragma unroll
            for (int reg = 0; reg < 4; ++reg) {
                u32 pk = mvp[t][reg >> 1];
                float mval = bf2f((short)((reg & 1) ? (pk >> 16) : (pk & 0xffff)));
                float bt = bf2f(SA[BT2 + bidx[t][reg] + h]);
                p[t][reg] = sc[t][reg] + mval + bt;
            }
        #pragma unroll
        for (int reg = 0; reg < 4; ++reg) {
            float mx = fmaxf(fmaxf(p[0][reg], p[1][reg]), fmaxf(p[2][reg], p[3][reg]));
            #pragma unroll
            for (int off = 8; off >= 1; off >>= 1) mx = fmaxf(mx, __shfl_xor(mx, off, 64));
            float s0 = 0.f;
            #pragma unroll
            for (int t = 0; t < 4; ++t) { p[t][reg] = __expf(p[t][reg] - mx); s0 += p[t][reg]; }
            #pragma unroll
            for (int off = 8; off >= 1; off >>= 1) s0 += __shfl_xor(s0, off, 64);
            float rs = 1.f / s0;
            #pragma unroll
            for (int t = 0; t < 4; ++t) p[t][reg] *= rs;
        }
        #pragma unroll
        for (int t = 0; t < 4; ++t)
            #pragma unroll
            for (int reg = 0; reg < 4; ++reg) {
                int r = l4 * 4 + reg;
                int byt = r * 128 + ((((t * 16 + l15) << 1)) ^ ((r & 7) << 4));
                SA[PS2 + wv * 1024 + (byt >> 1)] = f2bf(p[t][reg]);
            }
        f32x4 av[2];
        av[0] = zf; av[1] = zf;
        #pragma unroll
        for (int kst = 0; kst < 2; ++kst) {
            short8 pa;
            {
                int byt = l15 * 128 + (((kst * 64 + l4 * 16)) ^ ((l15 & 7) << 4));
                pa = *(const short8*)&SA[PS2 + wv * 1024 + (byt >> 1)];
            }
            #pragma unroll
            for (int dt = 0; dt < 2; ++dt)
                av[dt] = __builtin_amdgcn_mfma_f32_16x16x32_bf16(pa, vf[dt * 2 + kst], av[dt], 0, 0, 0);
        }
        #pragma unroll
        for (int dt = 0; dt < 2; ++dt)
            #pragma unroll
            for (int reg = 0; reg < 4; ++reg) {
                int tok = wv * 16 + l4 * 4 + reg;
                if (tok < NTOK) {
                    int r = (wl & 1) * 64 + tok;
                    int inner = ((((h & 1) << 6) | ((dt * 16 + l15) << 1))) ^ ((r & 7) << 4);
                    *(short*)(avb + (size_t)((wl >> 1) * 6 + (h >> 1)) * 16384 + r * 128 + inner)
                        = f2bf(av[dt][reg]);
                }
            }
    }
}

// ======= proj_pad: out = AV @ projW^T + b, padded M tiles, XCD-grouped bids =======
__global__ __launch_bounds__(256, 2)
void proj_pad(const char* __restrict__ avb, const short* __restrict__ wpb,
              const float* __restrict__ proj_b, float* __restrict__ out, int mb0)
{
    __shared__ char LC[2][32768] __attribute__((aligned(128)));

    const int tid = threadIdx.x;
    const int wv = tid >> 6, lane = tid & 63;
    const int l15 = lane & 15, l4 = lane >> 4;
    const int wr = wv >> 1, wc = wv & 1;
    const int sg = blockIdx.x / 24, bb = blockIdx.x % 24;
    const int mb = sg * 8 + (bb & 7), nb = bb >> 3;

    const char* asrc = avb + (size_t)mb * 6 * 16384;
    const char* bsrc = (const char*)wpb + (size_t)nb * 6 * 16384;

    f32x4 acc[4][4];
    #pragma unroll
    for (int mi = 0; mi < 4; ++mi)
        #pragma unroll
        for (int ni = 0; ni < 4; ++ni) acc[mi][ni] = (f32x4){0.f, 0.f, 0.f, 0.f};

    #pragma unroll
    for (int it = 0; it < 4; ++it) {
        int L = (wv * 4 + it) * 1024;
        gld_lds16(asrc + L + lane * 16, &LC[0][L]);
        gld_lds16(bsrc + L + lane * 16, &LC[0][16384 + L]);
    }

    #pragma unroll
    for (int kc = 0; kc < 6; ++kc) {
        __builtin_amdgcn_sched_barrier(0);
        asm volatile("s_waitcnt vmcnt(0)" ::: "memory");
        __builtin_amdgcn_s_barrier();
        __builtin_amdgcn_sched_barrier(0);
        if (kc < 5) {
            #pragma unroll
            for (int it = 0; it < 4; ++it) {
                int L = (wv * 4 + it) * 1024;
                gld_lds16(asrc + (kc + 1) * 16384 + L + lane * 16, &LC[(kc + 1) & 1][L]);
                gld_lds16(bsrc + (kc + 1) * 16384 + L + lane * 16, &LC[(kc + 1) & 1][16384 + L]);
            }
        }
        const char* bufp = LC[kc & 1];
        __builtin_amdgcn_s_setprio(1);
        #pragma unroll
        for (int ksub = 0; ksub < 2; ++ksub) {
            short8 a[4], b[4];
            #pragma unroll
            for (int mi = 0; mi < 4; ++mi) {
                int row = wr * 64 + mi * 16 + l15;
                a[mi] = *(const short8*)(bufp + row * 128 +
                        ((ksub * 64 + l4 * 16) ^ ((row & 7) << 4)));
            }
            #pragma unroll
            for (int ni = 0; ni < 4; ++ni) {
                int row = wc * 64 + ni * 16 + l15;
                b[ni] = *(const short8*)(bufp + 16384 + row * 128 +
                        ((ksub * 64 + l4 * 16) ^ ((row & 7) << 4)));
            }
            #pragma unroll
            for (int mi = 0; mi < 4; ++mi)
                #pragma unroll
                for (int ni = 0; ni < 4; ++ni)
                    acc[mi][ni] = __builtin_amdgcn_mfma_f32_16x16x32_bf16(
                        a[mi], b[ni], acc[mi][ni], 0, 0, 0);
        }
        __builtin_amdgcn_s_setprio(0);
    }

    float pb[4];
    #pragma unroll
    for (int ni = 0; ni < 4; ++ni) pb[ni] = proj_b[nb * 128 + wc * 64 + ni * 16 + l15];
    const int wg = (mb0 + mb) * 2 + wr;
    #pragma unroll
    for (int mi = 0; mi < 4; ++mi) {
        #pragma unroll
        for (int ni = 0; ni < 4; ++ni) {
            #pragma unroll
            for (int reg = 0; reg < 4; ++reg) {
                int tok = mi * 16 + l4 * 4 + reg;
                if (tok < NTOK)
                    out[((size_t)wg * NTOK + tok) * DIMC + nb * 128 + wc * 64 + ni * 16 + l15]
                        = acc[mi][ni][reg] + pb[ni];
            }
        }
    }
}

// ================= fallback: monolithic gather kernel (no ws) =================
__global__ __launch_bounds__(256, 2)
void winattn_fallback(const float* __restrict__ x, const float* __restrict__ mask,
                      const float* __restrict__ qkv_w, const float* __restrict__ qkv_b,
                      const float* __restrict__ proj_w, const float* __restrict__ proj_b,
                      const float* __restrict__ bias_table, float* __restrict__ out)
{
    __shared__ short SL[26624] __attribute__((aligned(128)));
    const int tid = threadIdx.x, wv = tid >> 6, lane = tid & 63;
    const int l15 = lane & 15, l4 = lane >> 4;
    const int win = blockIdx.x;
    const int xbase = win * (NTOK * DIMC);
    const int KSo = 0, VTo = 2048, PSo = 4096, QAo = 8192;

    short8 xf[12];
    {
        const int row = wv * 16 + l15;
        const bool valid = row < NTOK;
        const float* xr = x + xbase + row * DIMC;
        #pragma unroll
        for (int ks = 0; ks < 12; ++ks)
            xf[ks] = valid ? gather_bf(xr, 0, ks * 32 + l4 * 8) : (short8)0;
    }
    float mv[4][4]; int bidx[4][4]; float negm[4];
    {
        const float* maskp = mask + (win & 63) * (NTOK * NTOK);
        int cofi[4], cofm[4];
        #pragma unroll
        for (int t = 0; t < 4; ++t) {
            int m = t * 16 + l15;
            negm[t] = (m < NTOK) ? 0.f : -1e30f;
            cofm[t] = cof(48 - (m < NTOK ? m : 48));
            #pragma unroll
            for (int reg = 0; reg < 4; ++reg) {
                int i = wv * 16 + l4 * 4 + reg;
                mv[t][reg] = (i < NTOK && m < NTOK) ? maskp[i * NTOK + m] : 0.f;
            }
        }
        #pragma unroll
        for (int reg = 0; reg < 4; ++reg) {
            int i = wv * 16 + l4 * 4 + reg;
            cofi[reg] = cof(i < NTOK ? i : 48);
        }
        #pragma unroll
        for (int t = 0; t < 4; ++t)
            #pragma unroll
            for (int reg = 0; reg < 4; ++reg) bidx[t][reg] = (cofi[reg] + cofm[t]) * NH;
    }
    f32x4 pacc[24];
    #pragma unroll
    for (int t = 0; t < 24; ++t) pacc[t] = (f32x4){0.f, 0.f, 0.f, 0.f};
    const f32x4 zf = (f32x4){0.f, 0.f, 0.f, 0.f};
    __syncthreads();

    #pragma unroll 1
    for (int h = 0; h < NH; ++h) {
        f32x4 qa[6];
        #pragma unroll
        for (int nt = 0; nt < 6; ++nt) qa[nt] = zf;
        #pragma unroll
        for (int nt = 0; nt < 6; ++nt) {
            const int grow = (nt >> 1) * DIMC + h * 32 + (nt & 1) * 16 + l15;
            #pragma unroll
            for (int ks = 0; ks < 12; ++ks) {
                short8 b = gather_bf(qkv_w, grow, ks * 32 + l4 * 8);
                qa[nt] = __builtin_amdgcn_mfma_f32_16x16x32_bf16(xf[ks], b, qa[nt], 0, 0, 0);
            }
        }
        #pragma unroll
        for (int nt = 0; nt < 6; ++nt) {
            const int sub = nt >> 1;
            const int colw = (nt & 1) * 16 + l15;
            const float bias = qkv_b[sub * DIMC + h * 32 + colw];
            #pragma unroll
            for (int reg = 0; reg < 4; ++reg) {
                const int tokg = wv * 16 + l4 * 4 + reg;
                float val = qa[nt][reg] + bias;
                if (sub == 0) {
                    int byt = tokg * 64 + ((colw << 1) ^ ((tokg & 3) << 4));
                    SL[QAo + (byt >> 1)] = f2bf(val * QSCALE);
                } else if (sub == 1) {
                    int byt = tokg * 64 + ((colw << 1) ^ ((tokg & 3) << 4));
                    SL[KSo + (byt >> 1)] = f2bf(val);
                } else {
                    int byt = colw * 128 + ((tokg << 1) ^ ((colw & 7) << 4));
                    SL[VTo + (byt >> 1)] = f2bf(val);
                }
            }
        }
        __syncthreads();
        short8 aq;
        { int row = wv*16+l15; int byt = row*64 + ((l4*16) ^ ((row&3)<<4));
          aq = *(const short8*)&SL[QAo + (byt>>1)]; }
        f32x4 sc[4];
        #pragma unroll
        for (int t = 0; t < 4; ++t) {
            int row = t*16+l15; int byt = row*64 + ((l4*16) ^ ((row&3)<<4));
            short8 bk = *(const short8*)&SL[KSo + (byt>>1)];
            sc[t] = __builtin_amdgcn_mfma_f32_16x16x32_bf16(aq, bk, zf, 0, 0, 0);
        }
        float p[4][4];
        #pragma unroll
        for (int t = 0; t < 4; ++t)
            #pragma unroll
            for (int reg = 0; reg < 4; ++reg)
                p[t][reg] = sc[t][reg] + mv[t][reg] + bias_table[bidx[t][reg] + h] + negm[t];
        #pragma unroll
        for (int reg = 0; reg < 4; ++reg) {
            float mx = fmaxf(fmaxf(p[0][reg], p[1][reg]), fmaxf(p[2][reg], p[3][reg]));
            #pragma unroll
            for (int off = 8; off >= 1; off >>= 1) mx = fmaxf(mx, __shfl_xor(mx, off, 64));
            float s0 = 0.f;
            #pragma unroll
            for (int t = 0; t < 4; ++t) { p[t][reg] = __expf(p[t][reg] - mx); s0 += p[t][reg]; }
            #pragma unroll
            for (int off = 8; off >= 1; off >>= 1) s0 += __shfl_xor(s0, off, 64);
            float rs = 1.f / s0;
            #pragma unroll
            for (int t = 0; t < 4; ++t) p[t][reg] *= rs;
        }
        #pragma unroll
        for (int t = 0; t < 4; ++t)
            #pragma unroll
            for (int reg = 0; reg < 4; ++reg) {
                int row = wv*16 + l4*4 + reg;
                int byt = row*128 + (((t*16+l15) << 1) ^ ((row&7)<<4));
                SL[PSo + (byt>>1)] = f2bf(p[t][reg]);
            }
        f32x4 av[2]; av[0] = zf; av[1] = zf;
        #pragma unroll
        for (int kst = 0; kst < 2; ++kst) {
            short8 pa;
            { int row = wv*16+l15; int byt = row*128 + ((kst*64+l4*16) ^ ((row&7)<<4));
              pa = *(const short8*)&SL[PSo + (byt>>1)]; }
            #pragma unroll
            for (int dt = 0; dt < 2; ++dt) {
                int d = dt*16+l15; int byt = d*128 + ((kst*64+l4*16) ^ ((d&7)<<4));
                short8 bv = *(const short8*)&SL[VTo + (byt>>1)];
                av[dt] = __builtin_amdgcn_mfma_f32_16x16x32_bf16(pa, bv, av[dt], 0, 0, 0);
            }
        }
        __syncthreads();
        #pragma unroll
        for (int dt = 0; dt < 2; ++dt)
            #pragma unroll
            for (int reg = 0; reg < 4; ++reg) {
                int row = wv*16 + l4*4 + reg;
                int byt = row*64 + (((dt*16+l15) << 1) ^ ((row&3)<<4));
                SL[QAo + (byt>>1)] = f2bf(av[dt][reg]);
            }
        __syncthreads();
        short8 aa;
        { int row = wv*16+l15; int byt = row*64 + ((l4*16) ^ ((row&3)<<4));
          aa = *(const short8*)&SL[QAo + (byt>>1)]; }
        #pragma unroll
        for (int nt = 0; nt < 24; ++nt) {
            short8 bp = gather_bf(proj_w, nt * 16 + l15, h * 32 + l4 * 8);
            pacc[nt] = __builtin_amdgcn_mfma_f32_16x16x32_bf16(aa, bp, pacc[nt], 0, 0, 0);
        }
    }
    {
        float* op = out + xbase;
        #pragma unroll
        for (int nt = 0; nt < 24; ++nt) {
            const float pb = proj_b[nt * 16 + l15];
            #pragma unroll
            for (int reg = 0; reg < 4; ++reg) {
                const int i = wv * 16 + l4 * 4 + reg;
                if (i < NTOK) op[i * DIMC + nt * 16 + l15] = pacc[nt][reg] + pb;
            }
        }
    }
}

extern "C" void kernel_launch(void* const* d_in, const int* in_sizes, int n_in,
                              void* d_out, int out_size, void* d_ws, size_t ws_size,
                              hipStream_t stream) {
    const float* x          = (const float*)d_in[0];
    const float* mask       = (const float*)d_in[1];
    const float* qkv_w      = (const float*)d_in[2];
    const float* qkv_b      = (const float*)d_in[3];
    const float* proj_w     = (const float*)d_in[4];
    const float* proj_b     = (const float*)d_in[5];
    const float* bias_table = (const float*)d_in[6];
    float* out = (float*)d_out;

    const size_t fixed = ((size_t)WQB2_SHORTS + WPB_SHORTS) * 2;
    auto need = [&](int c) {
        size_t wpc = 4096 / c;
        size_t mbc = wpc / 2;
        return fixed + mbc * 98304UL /*xa*/ + wpc * 147456UL /*qkvb*/ + mbc * 98304UL /*avb*/;
    };
    int c = 0;
    if (ws_size >= need(8)) c = 8;
    else if (ws_size >= need(16)) c = 16;

    if (c) {
        short* wqb2 = (short*)d_ws;
        short* wpb  = wqb2 + WQB2_SHORTS;
        const int wpc = 4096 / c;
        const int mbc = wpc / 2;
        short* xa   = wpb + WPB_SHORTS;
        short* qkvb = xa + (size_t)mbc * 49152;
        char*  avb  = (char*)(qkvb + (size_t)wpc * 73728);

        prep2<<<288, 256, 0, stream>>>(qkv_w, proj_w, wqb2, wpb);
        for (int ch = 0; ch < c; ++ch) {
            const int w0 = ch * wpc;
            prep_x<<<mbc * 6, 1024, 0, stream>>>(x, xa, w0);
            qkv_gemm<<<mbc * 9, 256, 0, stream>>>(xa, qkv_b, wqb2, qkvb);
            attn_win<<<wpc, 256, 0, stream>>>(mask, bias_table, qkvb, avb, w0);
            proj_pad<<<mbc * 3, 256, 0, stream>>>(avb, wpb, proj_b, out, ch * mbc);
        }
    } else {
        winattn_fallback<<<4096, 256, 0, stream>>>(x, mask, qkv_w, qkv_b, proj_w,
                                                   proj_b, bias_table, out);
    }
}

// Round 12
// 784.752 us; speedup vs baseline: 1.3061x; 1.0311x over previous
//
#include <hip/hip_runtime.h>
#include <hip/hip_bf16.h>

#define NTOK 49
#define DIMC 384
#define NH 12
#define QSCALE 0.17677669529663687f

typedef __attribute__((ext_vector_type(8))) short short8;
typedef __attribute__((ext_vector_type(4))) float f32x4;
typedef unsigned int u32;

#define WQB2_SHORTS (54 * 8192)
#define WPB_SHORTS  (18 * 8192)

__device__ __forceinline__ short f2bf(float f) {
    __bf16 h = (__bf16)f;
    return __builtin_bit_cast(short, h);
}
__device__ __forceinline__ float bf2f(short s) {
    u32 u = ((u32)(unsigned short)s) << 16;
    return __builtin_bit_cast(float, u);
}
__device__ __forceinline__ int cof(int p) { return 13 * (p / 7) + (p % 7); }

__device__ __forceinline__ void gld_lds16(const void* g, void* l) {
    __builtin_amdgcn_global_load_lds(
        (const __attribute__((address_space(1))) u32*)g,
        (__attribute__((address_space(3))) u32*)l, 16, 0, 0);
}

__device__ __forceinline__ short8 gather_bf(const float* __restrict__ w, int row, int k0) {
    const float* p = w + row * DIMC + k0;
    float4 a = *(const float4*)p;
    float4 b = *(const float4*)(p + 4);
    short8 r;
    r[0]=f2bf(a.x); r[1]=f2bf(a.y); r[2]=f2bf(a.z); r[3]=f2bf(a.w);
    r[4]=f2bf(b.x); r[5]=f2bf(b.y); r[6]=f2bf(b.z); r[7]=f2bf(b.w);
    return r;
}

// ---------------- prep2: swizzled 128x64 B-tiles for qkv (9 nb) + proj (3 nb) ----------------
__global__ void prep2(const float* __restrict__ qw, const float* __restrict__ pw,
                      short* __restrict__ wqb2, short* __restrict__ wpb) {
    int gt = blockIdx.x * 256 + threadIdx.x;    // 73728 total
    int tile = gt >> 10;
    int rem = gt & 1023;
    int r = rem >> 3, g = rem & 7;
    int kc = tile % 6;
    int k0 = kc * 64 + ((g ^ (r & 7)) << 3);
    short8 o;
    if (tile < 54) {
        int nb = tile / 6;
        const float* src = qw + (size_t)(nb * 128 + r) * DIMC + k0;
        #pragma unroll
        for (int e = 0; e < 8; ++e) o[e] = f2bf(src[e]);
        *(short8*)(wqb2 + (size_t)tile * 8192 + r * 64 + g * 8) = o;
    } else {
        int t2 = tile - 54;
        int nb = t2 / 6;
        const float* src = pw + (size_t)(nb * 128 + r) * DIMC + k0;
        #pragma unroll
        for (int e = 0; e < 8; ++e) o[e] = f2bf(src[e]);
        *(short8*)(wpb + (size_t)t2 * 8192 + r * 64 + g * 8) = o;
    }
}

// ---------------- prep_x: x -> bf16 pre-swizzled padded A-tiles (per chunk) ----------------
__global__ __launch_bounds__(1024)
void prep_x(const float* __restrict__ x, short* __restrict__ xa, int w0) {
    const int bid = blockIdx.x;
    const int mt = bid / 6, kc = bid % 6;
    const int tid = threadIdx.x;
    const int r = tid >> 3, g = tid & 7;
    const int win = w0 + mt * 2 + (r >> 6);
    const int tok = r & 63;
    const int k0 = kc * 64 + ((g ^ (r & 7)) << 3);
    short8 o;
    if (tok < NTOK) {
        const float* src = x + ((size_t)win * NTOK + tok) * DIMC + k0;
        float4 a = *(const float4*)src;
        float4 b = *(const float4*)(src + 4);
        o[0]=f2bf(a.x); o[1]=f2bf(a.y); o[2]=f2bf(a.z); o[3]=f2bf(a.w);
        o[4]=f2bf(b.x); o[5]=f2bf(b.y); o[6]=f2bf(b.z); o[7]=f2bf(b.w);
    } else {
        o = (short8)0;
    }
    *(short8*)(xa + ((size_t)mt * 6 + kc) * 8192 + r * 64 + g * 8) = o;
}

// ======= qkv_gemm: 128x128xK pipeline (A from xa, B from wqb2), frag-layout epilogue =======
__global__ __launch_bounds__(256, 2)
void qkv_gemm(const short* __restrict__ xa, const float* __restrict__ qkv_b,
              const short* __restrict__ wqb2, short* __restrict__ qkvb)
{
    __shared__ char LC[2][32768] __attribute__((aligned(128)));

    const int tid = threadIdx.x;
    const int wv = tid >> 6, lane = tid & 63;
    const int l15 = lane & 15, l4 = lane >> 4;
    const int wr = wv >> 1, wc = wv & 1;
    const int sg = blockIdx.x / 72, bb = blockIdx.x % 72;
    const int mb = sg * 8 + (bb & 7), nb = bb >> 3;

    const char* asrc = (const char*)xa + (size_t)mb * 6 * 16384;
    const char* bsrc = (const char*)wqb2 + (size_t)(nb * 6) * 8192 * 2;

    f32x4 acc[4][4];
    #pragma unroll
    for (int mi = 0; mi < 4; ++mi)
        #pragma unroll
        for (int ni = 0; ni < 4; ++ni) acc[mi][ni] = (f32x4){0.f, 0.f, 0.f, 0.f};

    #pragma unroll
    for (int it = 0; it < 4; ++it) {
        int L = (wv * 4 + it) * 1024;
        gld_lds16(asrc + L + lane * 16, &LC[0][L]);
        gld_lds16(bsrc + L + lane * 16, &LC[0][16384 + L]);
    }

    #pragma unroll
    for (int kc = 0; kc < 6; ++kc) {
        __builtin_amdgcn_sched_barrier(0);
        asm volatile("s_waitcnt vmcnt(0)" ::: "memory");
        __builtin_amdgcn_s_barrier();
        __builtin_amdgcn_sched_barrier(0);
        if (kc < 5) {
            #pragma unroll
            for (int it = 0; it < 4; ++it) {
                int L = (wv * 4 + it) * 1024;
                gld_lds16(asrc + (kc + 1) * 16384 + L + lane * 16, &LC[(kc + 1) & 1][L]);
                gld_lds16(bsrc + (kc + 1) * 16384 + L + lane * 16, &LC[(kc + 1) & 1][16384 + L]);
            }
        }
        const char* bufp = LC[kc & 1];
        __builtin_amdgcn_s_setprio(1);
        #pragma unroll
        for (int ksub = 0; ksub < 2; ++ksub) {
            short8 a[4], b[4];
            #pragma unroll
            for (int mi = 0; mi < 4; ++mi) {
                int row = wr * 64 + mi * 16 + l15;
                a[mi] = *(const short8*)(bufp + row * 128 +
                        ((ksub * 64 + l4 * 16) ^ ((row & 7) << 4)));
            }
            #pragma unroll
            for (int ni = 0; ni < 4; ++ni) {
                int row = wc * 64 + ni * 16 + l15;
                b[ni] = *(const short8*)(bufp + 16384 + row * 128 +
                        ((ksub * 64 + l4 * 16) ^ ((row & 7) << 4)));
            }
            #pragma unroll
            for (int mi = 0; mi < 4; ++mi)
                #pragma unroll
                for (int ni = 0; ni < 4; ++ni)
                    acc[mi][ni] = __builtin_amdgcn_mfma_f32_16x16x32_bf16(
                        a[mi], b[ni], acc[mi][ni], 0, 0, 0);
        }
        __builtin_amdgcn_s_setprio(0);
    }

    __syncthreads();   // all phases done before LC reuse as transpose slabs

    float bias[4];
    #pragma unroll
    for (int ni = 0; ni < 4; ++ni) bias[ni] = qkv_b[nb * 128 + wc * 64 + ni * 16 + l15];

    char* slab = (char*)LC + wv * 8192;   // 64 rows x 128B, wave-private
    const int wl = mb * 2 + wr;           // local window
    const int sub = nb / 3;               // 0=q 1=k 2=v

    if (sub < 2) {
        #pragma unroll
        for (int mi = 0; mi < 4; ++mi)
            #pragma unroll
            for (int ni = 0; ni < 4; ++ni)
                #pragma unroll
                for (int reg = 0; reg < 4; ++reg) {
                    float v = acc[mi][ni][reg] + bias[ni];
                    if (sub == 0) v *= QSCALE;
                    int rowp = mi * 16 + l4 * 4 + reg, colp = ni * 16 + l15;
                    *(short*)(slab + rowp * 128 + ((colp * 2) ^ ((rowp & 7) << 4))) = f2bf(v);
                }
        __builtin_amdgcn_sched_barrier(0);
        asm volatile("s_waitcnt lgkmcnt(0)" ::: "memory");
        __builtin_amdgcn_sched_barrier(0);
        #pragma unroll
        for (int hh = 0; hh < 2; ++hh)
            #pragma unroll
            for (int s = 0; s < 4; ++s) {
                int head = (nb % 3) * 4 + wc * 2 + hh;
                int rowp = s * 16 + l15;
                short8 frag = *(const short8*)(slab + rowp * 128 +
                              ((hh * 64 + l4 * 16) ^ ((rowp & 7) << 4)));
                *(short8*)(qkvb + (((size_t)wl * NH + head) * 12 + sub * 4 + s) * 512 + lane * 8) = frag;
            }
    } else {
        #pragma unroll
        for (int mi = 0; mi < 4; ++mi)
            #pragma unroll
            for (int ni = 0; ni < 4; ++ni)
                #pragma unroll
                for (int reg = 0; reg < 4; ++reg) {
                    float v = acc[mi][ni][reg] + bias[ni];
                    int rowp = mi * 16 + l4 * 4 + reg, colp = ni * 16 + l15;
                    *(short*)(slab + colp * 128 + ((rowp * 2) ^ ((colp & 7) << 4))) = f2bf(v);
                }
        __builtin_amdgcn_sched_barrier(0);
        asm volatile("s_waitcnt lgkmcnt(0)" ::: "memory");
        __builtin_amdgcn_sched_barrier(0);
        #pragma unroll
        for (int hh = 0; hh < 2; ++hh)
            #pragma unroll
            for (int dt = 0; dt < 2; ++dt)
                #pragma unroll
                for (int kst = 0; kst < 2; ++kst) {
                    int head = (nb - 6) * 4 + wc * 2 + hh;
                    int row2 = hh * 32 + dt * 16 + l15;
                    short8 frag = *(const short8*)(slab + row2 * 128 +
                                  ((kst * 64 + l4 * 16) ^ ((row2 & 7) << 4)));
                    *(short8*)(qkvb + (((size_t)wl * NH + head) * 12 + 8 + dt * 2 + kst) * 512 + lane * 8) = frag;
                }
    }
}

// ======= attnproj: 1 block = 2 windows; attention -> AV in LDS -> proj -> out =======
// LDS: AVS [128 rows][768B swz] 98304 | PS 8x2048 | BT 4096 | BB 2x16384
#define AVS_OFF 0
#define PSW_OFF 98304
#define BTT_OFF 114688
#define BBB_OFF 118784
#define APL_TOT 151552

__global__ __launch_bounds__(512)
void attnproj(const float* __restrict__ mask, const float* __restrict__ bias_table,
              const short* __restrict__ qkvb, const short* __restrict__ wpb,
              const float* __restrict__ proj_b, float* __restrict__ out, int w0)
{
    __shared__ char SB[APL_TOT] __attribute__((aligned(128)));
    short* BT = (short*)(SB + BTT_OFF);

    const int tid = threadIdx.x;
    const int wv = tid >> 6, lane = tid & 63;
    const int l15 = lane & 15, l4 = lane >> 4;
    const int wl = wv >> 2;        // window within block (0/1)
    const int st4 = wv & 3;        // q-stripe within window
    const int lw = blockIdx.x * 2 + wl;   // local window in chunk
    const int win = w0 + lw;

    for (int i = tid; i < 169 * NH; i += 512) BT[i] = f2bf(bias_table[i]);

    // mask packed bf16 pairs (col-pad folded) + rel-idx, for stripe st4
    u32 mvp[4][2];
    int bidx[4][4];
    {
        const float* maskp = mask + (size_t)(win & 63) * (NTOK * NTOK);
        #pragma unroll
        for (int t = 0; t < 4; ++t) {
            int m = t * 16 + l15;
            float pad = (m < NTOK) ? 0.f : -1e30f;
            #pragma unroll
            for (int rp = 0; rp < 2; ++rp) {
                float v[2];
                #pragma unroll
                for (int e = 0; e < 2; ++e) {
                    int i = st4 * 16 + l4 * 4 + rp * 2 + e;
                    v[e] = ((i < NTOK && m < NTOK) ? maskp[i * NTOK + m] : 0.f) + pad;
                }
                mvp[t][rp] = (u32)(unsigned short)f2bf(v[0]) |
                             ((u32)(unsigned short)f2bf(v[1]) << 16);
            }
        }
        int cofi[4], cofm[4];
        #pragma unroll
        for (int t = 0; t < 4; ++t) {
            int m = t * 16 + l15;
            cofm[t] = cof(48 - (m < NTOK ? m : 48));
        }
        #pragma unroll
        for (int reg = 0; reg < 4; ++reg) {
            int i = st4 * 16 + l4 * 4 + reg;
            cofi[reg] = cof(i < NTOK ? i : 48);
        }
        #pragma unroll
        for (int t = 0; t < 4; ++t)
            #pragma unroll
            for (int reg = 0; reg < 4; ++reg)
                bidx[t][reg] = (cofi[reg] + cofm[t]) * NH;
    }
    const f32x4 zf = (f32x4){0.f, 0.f, 0.f, 0.f};
    __syncthreads();   // BT visible

    const short* qh = qkvb + (size_t)lw * (NH * 12 * 512);
    char* psw = SB + PSW_OFF + wv * 2048;

    // ---------------- attention: 12 heads, zero block barriers ----------------
    #pragma unroll 1
    for (int h = 0; h < NH; ++h) {
        const short* hb = qh + h * (12 * 512) + lane * 8;
        short8 q = *(const short8*)(hb + st4 * 512);
        short8 kf[4], vf[4];
        #pragma unroll
        for (int t = 0; t < 4; ++t) kf[t] = *(const short8*)(hb + (4 + t) * 512);
        #pragma unroll
        for (int j = 0; j < 4; ++j) vf[j] = *(const short8*)(hb + (8 + j) * 512);

        f32x4 sc[4];
        #pragma unroll
        for (int t = 0; t < 4; ++t)
            sc[t] = __builtin_amdgcn_mfma_f32_16x16x32_bf16(q, kf[t], zf, 0, 0, 0);

        float p[4][4];
        #pragma unroll
        for (int t = 0; t < 4; ++t)
            #pragma unroll
            for (int reg = 0; reg < 4; ++reg) {
                u32 pk = mvp[t][reg >> 1];
                float mval = bf2f((short)((reg & 1) ? (pk >> 16) : (pk & 0xffff)));
                float bt = bf2f(BT[bidx[t][reg] + h]);
                p[t][reg] = sc[t][reg] + mval + bt;
            }
        #pragma unroll
        for (int reg = 0; reg < 4; ++reg) {
            float mx = fmaxf(fmaxf(p[0][reg], p[1][reg]), fmaxf(p[2][reg], p[3][reg]));
            #pragma unroll
            for (int off = 8; off >= 1; off >>= 1) mx = fmaxf(mx, __shfl_xor(mx, off, 64));
            float s0 = 0.f;
            #pragma unroll
            for (int t = 0; t < 4; ++t) { p[t][reg] = __expf(p[t][reg] - mx); s0 += p[t][reg]; }
            #pragma unroll
            for (int off = 8; off >= 1; off >>= 1) s0 += __shfl_xor(s0, off, 64);
            float rs = 1.f / s0;
            #pragma unroll
            for (int t = 0; t < 4; ++t) p[t][reg] *= rs;
        }
        // P -> per-wave slab (swizzled 128B rows)
        #pragma unroll
        for (int t = 0; t < 4; ++t)
            #pragma unroll
            for (int reg = 0; reg < 4; ++reg) {
                int r = l4 * 4 + reg;
                int byt = r * 128 + ((((t * 16 + l15) << 1)) ^ ((r & 7) << 4));
                *(short*)(psw + byt) = f2bf(p[t][reg]);
            }
        // PV
        f32x4 av[2];
        av[0] = zf; av[1] = zf;
        #pragma unroll
        for (int kst = 0; kst < 2; ++kst) {
            short8 pa;
            {
                int byt = l15 * 128 + (((kst * 64 + l4 * 16)) ^ ((l15 & 7) << 4));
                pa = *(const short8*)(psw + byt);
            }
            #pragma unroll
            for (int dt = 0; dt < 2; ++dt)
                av[dt] = __builtin_amdgcn_mfma_f32_16x16x32_bf16(pa, vf[dt * 2 + kst], av[dt], 0, 0, 0);
        }
        // AV -> AVS LDS (row = wl*64+tok, col = h*32+d, swizzled like proj A-frags)
        #pragma unroll
        for (int dt = 0; dt < 2; ++dt)
            #pragma unroll
            for (int reg = 0; reg < 4; ++reg) {
                int tok = st4 * 16 + l4 * 4 + reg;
                if (tok < NTOK) {
                    int row = wl * 64 + tok;
                    int lb = (h * 32 + dt * 16 + l15) * 2;
                    *(short*)(SB + AVS_OFF + row * 768 + (lb ^ ((row & 7) << 4))) = f2bf(av[dt][reg]);
                }
            }
    }

    asm volatile("s_waitcnt lgkmcnt(0)" ::: "memory");
    __builtin_amdgcn_s_barrier();
    __builtin_amdgcn_sched_barrier(0);

    // ---------------- proj: out[128pad, 384] = AVS @ wpb^T + b ----------------
    // waves: wr = wl (M-half = window), wc = st4 (N 32-col slice within nb)
    const char* bsrc = (const char*)wpb;
    char* BB = SB + BBB_OFF;

    // prologue: stage (nb=0,kc=0) into buf 0
    #pragma unroll
    for (int it = 0; it < 2; ++it) {
        int L = it * 8192 + wv * 1024;
        gld_lds16(bsrc + L + lane * 16, BB + L);
    }

    f32x4 acc[4][2];
    #pragma unroll
    for (int mi = 0; mi < 4; ++mi) { acc[mi][0] = zf; acc[mi][1] = zf; }

    #pragma unroll 1
    for (int t = 0; t < 18; ++t) {
        const int kc = t % 6, nb = t / 6;
        __builtin_amdgcn_sched_barrier(0);
        asm volatile("s_waitcnt vmcnt(0)" ::: "memory");
        __builtin_amdgcn_s_barrier();
        __builtin_amdgcn_sched_barrier(0);
        if (t < 17) {
            #pragma unroll
            for (int it = 0; it < 2; ++it) {
                int L = it * 8192 + wv * 1024;
                gld_lds16(bsrc + (size_t)(t + 1) * 16384 + L + lane * 16,
                          BB + ((t + 1) & 1) * 16384 + L);
            }
        }
        const char* bufp = BB + (t & 1) * 16384;
        __builtin_amdgcn_s_setprio(1);
        #pragma unroll
        for (int ksub = 0; ksub < 2; ++ksub) {
            short8 a[4], b[2];
            #pragma unroll
            for (int mi = 0; mi < 4; ++mi) {
                int row = wl * 64 + mi * 16 + l15;
                a[mi] = *(const short8*)(SB + AVS_OFF + row * 768 +
                        ((kc * 128 + ksub * 64 + l4 * 16) ^ ((row & 7) << 4)));
            }
            #pragma unroll
            for (int ni = 0; ni < 2; ++ni) {
                int row = st4 * 32 + ni * 16 + l15;
                b[ni] = *(const short8*)(bufp + row * 128 +
                        ((ksub * 64 + l4 * 16) ^ ((row & 7) << 4)));
            }
            #pragma unroll
            for (int mi = 0; mi < 4; ++mi)
                #pragma unroll
                for (int ni = 0; ni < 2; ++ni)
                    acc[mi][ni] = __builtin_amdgcn_mfma_f32_16x16x32_bf16(
                        a[mi], b[ni], acc[mi][ni], 0, 0, 0);
        }
        __builtin_amdgcn_s_setprio(0);
        if (kc == 5) {
            // epilogue for this nb
            const int gw = win;   // wave's window (wl matches M-half)
            #pragma unroll
            for (int ni = 0; ni < 2; ++ni) {
                const int col = nb * 128 + st4 * 32 + ni * 16 + l15;
                const float pb = proj_b[col];
                #pragma unroll
                for (int mi = 0; mi < 4; ++mi)
                    #pragma unroll
                    for (int reg = 0; reg < 4; ++reg) {
                        int tok = mi * 16 + l4 * 4 + reg;
                        if (tok < NTOK)
                            out[((size_t)gw * NTOK + tok) * DIMC + col] = acc[mi][ni][reg] + pb;
                    }
            }
            #pragma unroll
            for (int mi = 0; mi < 4; ++mi) { acc[mi][0] = zf; acc[mi][1] = zf; }
        }
    }
}

// ================= fallback: monolithic gather kernel (no ws) =================
__global__ __launch_bounds__(256, 2)
void winattn_fallback(const float* __restrict__ x, const float* __restrict__ mask,
                      const float* __restrict__ qkv_w, const float* __restrict__ qkv_b,
                      const float* __restrict__ proj_w, const float* __restrict__ proj_b,
                      const float* __restrict__ bias_table, float* __restrict__ out)
{
    __shared__ short SL[26624] __attribute__((aligned(128)));
    const int tid = threadIdx.x, wv = tid >> 6, lane = tid & 63;
    const int l15 = lane & 15, l4 = lane >> 4;
    const int win = blockIdx.x;
    const int xbase = win * (NTOK * DIMC);
    const int KSo = 0, VTo = 2048, PSo = 4096, QAo = 8192;

    short8 xf[12];
    {
        const int row = wv * 16 + l15;
        const bool valid = row < NTOK;
        const float* xr = x + xbase + row * DIMC;
        #pragma unroll
        for (int ks = 0; ks < 12; ++ks)
            xf[ks] = valid ? gather_bf(xr, 0, ks * 32 + l4 * 8) : (short8)0;
    }
    float mv[4][4]; int bidx[4][4];
    {
        const float* maskp = mask + (win & 63) * (NTOK * NTOK);
        int cofi[4], cofm[4];
        float negm[4];
        #pragma unroll
        for (int t = 0; t < 4; ++t) {
            int m = t * 16 + l15;
            negm[t] = (m < NTOK) ? 0.f : -1e30f;
            cofm[t] = cof(48 - (m < NTOK ? m : 48));
            #pragma unroll
            for (int reg = 0; reg < 4; ++reg) {
                int i = wv * 16 + l4 * 4 + reg;
                mv[t][reg] = ((i < NTOK && m < NTOK) ? maskp[i * NTOK + m] : 0.f) + negm[t];
            }
        }
        #pragma unroll
        for (int reg = 0; reg < 4; ++reg) {
            int i = wv * 16 + l4 * 4 + reg;
            cofi[reg] = cof(i < NTOK ? i : 48);
        }
        #pragma unroll
        for (int t = 0; t < 4; ++t)
            #pragma unroll
            for (int reg = 0; reg < 4; ++reg) bidx[t][reg] = (cofi[reg] + cofm[t]) * NH;
    }
    f32x4 pacc[24];
    #pragma unroll
    for (int t = 0; t < 24; ++t) pacc[t] = (f32x4){0.f, 0.f, 0.f, 0.f};
    const f32x4 zf = (f32x4){0.f, 0.f, 0.f, 0.f};
    __syncthreads();

    #pragma unroll 1
    for (int h = 0; h < NH; ++h) {
        f32x4 qa[6];
        #pragma unroll
        for (int nt = 0; nt < 6; ++nt) qa[nt] = zf;
        #pragma unroll
        for (int nt = 0; nt < 6; ++nt) {
            const int grow = (nt >> 1) * DIMC + h * 32 + (nt & 1) * 16 + l15;
            #pragma unroll
            for (int ks = 0; ks < 12; ++ks) {
                short8 b = gather_bf(qkv_w, grow, ks * 32 + l4 * 8);
                qa[nt] = __builtin_amdgcn_mfma_f32_16x16x32_bf16(xf[ks], b, qa[nt], 0, 0, 0);
            }
        }
        #pragma unroll
        for (int nt = 0; nt < 6; ++nt) {
            const int sub = nt >> 1;
            const int colw = (nt & 1) * 16 + l15;
            const float bias = qkv_b[sub * DIMC + h * 32 + colw];
            #pragma unroll
            for (int reg = 0; reg < 4; ++reg) {
                const int tokg = wv * 16 + l4 * 4 + reg;
                float val = qa[nt][reg] + bias;
                if (sub == 0) {
                    int byt = tokg * 64 + ((colw << 1) ^ ((tokg & 3) << 4));
                    SL[QAo + (byt >> 1)] = f2bf(val * QSCALE);
                } else if (sub == 1) {
                    int byt = tokg * 64 + ((colw << 1) ^ ((tokg & 3) << 4));
                    SL[KSo + (byt >> 1)] = f2bf(val);
                } else {
                    int byt = colw * 128 + ((tokg << 1) ^ ((colw & 7) << 4));
                    SL[VTo + (byt >> 1)] = f2bf(val);
                }
            }
        }
        __syncthreads();
        short8 aq;
        { int row = wv*16+l15; int byt = row*64 + ((l4*16) ^ ((row&3)<<4));
          aq = *(const short8*)&SL[QAo + (byt>>1)]; }
        f32x4 sc[4];
        #pragma unroll
        for (int t = 0; t < 4; ++t) {
            int row = t*16+l15; int byt = row*64 + ((l4*16) ^ ((row&3)<<4));
            short8 bk = *(const short8*)&SL[KSo + (byt>>1)];
            sc[t] = __builtin_amdgcn_mfma_f32_16x16x32_bf16(aq, bk, zf, 0, 0, 0);
        }
        float p[4][4];
        #pragma unroll
        for (int t = 0; t < 4; ++t)
            #pragma unroll
            for (int reg = 0; reg < 4; ++reg)
                p[t][reg] = sc[t][reg] + mv[t][reg] + bias_table[bidx[t][reg] + h];
        #pragma unroll
        for (int reg = 0; reg < 4; ++reg) {
            float mx = fmaxf(fmaxf(p[0][reg], p[1][reg]), fmaxf(p[2][reg], p[3][reg]));
            #pragma unroll
            for (int off = 8; off >= 1; off >>= 1) mx = fmaxf(mx, __shfl_xor(mx, off, 64));
            float s0 = 0.f;
            #pragma unroll
            for (int t = 0; t < 4; ++t) { p[t][reg] = __expf(p[t][reg] - mx); s0 += p[t][reg]; }
            #pragma unroll
            for (int off = 8; off >= 1; off >>= 1) s0 += __shfl_xor(s0, off, 64);
            float rs = 1.f / s0;
            #pragma unroll
            for (int t = 0; t < 4; ++t) p[t][reg] *= rs;
        }
        #pragma unroll
        for (int t = 0; t < 4; ++t)
            #pragma unroll
            for (int reg = 0; reg < 4; ++reg) {
                int row = wv*16 + l4*4 + reg;
                int byt = row*128 + (((t*16+l15) << 1) ^ ((row&7)<<4));
                SL[PSo + (byt>>1)] = f2bf(p[t][reg]);
            }
        f32x4 av[2]; av[0] = zf; av[1] = zf;
        #pragma unroll
        for (int kst = 0; kst < 2; ++kst) {
            short8 pa;
            { int row = wv*16+l15; int byt = row*128 + ((kst*64+l4*16) ^ ((row&7)<<4));
              pa = *(const short8*)&SL[PSo + (byt>>1)]; }
            #pragma unroll
            for (int dt = 0; dt < 2; ++dt) {
                int d = dt*16+l15; int byt = d*128 + ((kst*64+l4*16) ^ ((d&7)<<4));
                short8 bv = *(const short8*)&SL[VTo + (byt>>1)];
                av[dt] = __builtin_amdgcn_mfma_f32_16x16x32_bf16(pa, bv, av[dt], 0, 0, 0);
            }
        }
        __syncthreads();
        #pragma unroll
        for (int dt = 0; dt < 2; ++dt)
            #pragma unroll
            for (int reg = 0; reg < 4; ++reg) {
                int row = wv*16 + l4*4 + reg;
                int byt = row*64 + (((dt*16+l15) << 1) ^ ((row&3)<<4));
                SL[QAo + (byt>>1)] = f2bf(av[dt][reg]);
            }
        __syncthreads();
        short8 aa;
        { int row = wv*16+l15; int byt = row*64 + ((l4*16) ^ ((row&3)<<4));
          aa = *(const short8*)&SL[QAo + (byt>>1)]; }
        #pragma unroll
        for (int nt = 0; nt < 24; ++nt) {
            short8 bp = gather_bf(proj_w, nt * 16 + l15, h * 32 + l4 * 8);
            pacc[nt] = __builtin_amdgcn_mfma_f32_16x16x32_bf16(aa, bp, pacc[nt], 0, 0, 0);
        }
    }
    {
        float* op = out + xbase;
        #pragma unroll
        for (int nt = 0; nt < 24; ++nt) {
            const float pb = proj_b[nt * 16 + l15];
            #pragma unroll
            for (int reg = 0; reg < 4; ++reg) {
                const int i = wv * 16 + l4 * 4 + reg;
                if (i < NTOK) op[i * DIMC + nt * 16 + l15] = pacc[nt][reg] + pb;
            }
        }
    }
}

extern "C" void kernel_launch(void* const* d_in, const int* in_sizes, int n_in,
                              void* d_out, int out_size, void* d_ws, size_t ws_size,
                              hipStream_t stream) {
    const float* x          = (const float*)d_in[0];
    const float* mask       = (const float*)d_in[1];
    const float* qkv_w      = (const float*)d_in[2];
    const float* qkv_b      = (const float*)d_in[3];
    const float* proj_w     = (const float*)d_in[4];
    const float* proj_b     = (const float*)d_in[5];
    const float* bias_table = (const float*)d_in[6];
    float* out = (float*)d_out;

    const size_t fixed = ((size_t)WQB2_SHORTS + WPB_SHORTS) * 2;
    auto need = [&](int c) {
        size_t wpc = 4096 / c;
        size_t mbc = wpc / 2;
        return fixed + mbc * 98304UL /*xa*/ + wpc * 147456UL /*qkvb*/;
    };
    int c = 0;
    if (ws_size >= need(4)) c = 4;
    else if (ws_size >= need(8)) c = 8;
    else if (ws_size >= need(16)) c = 16;

    if (c) {
        short* wqb2 = (short*)d_ws;
        short* wpb  = wqb2 + WQB2_SHORTS;
        const int wpc = 4096 / c;
        const int mbc = wpc / 2;
        short* xa   = wpb + WPB_SHORTS;
        short* qkvb = xa + (size_t)mbc * 49152;

        prep2<<<288, 256, 0, stream>>>(qkv_w, proj_w, wqb2, wpb);
        for (int ch = 0; ch < c; ++ch) {
            const int w0 = ch * wpc;
            prep_x<<<mbc * 6, 1024, 0, stream>>>(x, xa, w0);
            qkv_gemm<<<mbc * 9, 256, 0, stream>>>(xa, qkv_b, wqb2, qkvb);
            attnproj<<<mbc, 512, 0, stream>>>(mask, bias_table, qkvb, wpb, proj_b, out, w0);
        }
    } else {
        winattn_fallback<<<4096, 256, 0, stream>>>(x, mask, qkv_w, qkv_b, proj_w,
                                                   proj_b, bias_table, out);
    }
}

// Round 13
// 767.434 us; speedup vs baseline: 1.3356x; 1.0226x over previous
//
#include <hip/hip_runtime.h>
#include <hip/hip_bf16.h>

#define NTOK 49
#define DIMC 384
#define NH 12
#define QSCALE 0.17677669529663687f

typedef __attribute__((ext_vector_type(8))) short short8;
typedef __attribute__((ext_vector_type(4))) float f32x4;
typedef unsigned int u32;

#define WQB2_SHORTS (54 * 8192)
#define WPB_SHORTS  (18 * 8192)

__device__ __forceinline__ short f2bf(float f) {
    __bf16 h = (__bf16)f;
    return __builtin_bit_cast(short, h);
}
__device__ __forceinline__ float bf2f(short s) {
    u32 u = ((u32)(unsigned short)s) << 16;
    return __builtin_bit_cast(float, u);
}
__device__ __forceinline__ int cof(int p) { return 13 * (p / 7) + (p % 7); }

__device__ __forceinline__ void gld_lds16(const void* g, void* l) {
    __builtin_amdgcn_global_load_lds(
        (const __attribute__((address_space(1))) u32*)g,
        (__attribute__((address_space(3))) u32*)l, 16, 0, 0);
}

__device__ __forceinline__ short8 gather_bf(const float* __restrict__ w, int row, int k0) {
    const float* p = w + row * DIMC + k0;
    float4 a = *(const float4*)p;
    float4 b = *(const float4*)(p + 4);
    short8 r;
    r[0]=f2bf(a.x); r[1]=f2bf(a.y); r[2]=f2bf(a.z); r[3]=f2bf(a.w);
    r[4]=f2bf(b.x); r[5]=f2bf(b.y); r[6]=f2bf(b.z); r[7]=f2bf(b.w);
    return r;
}

// ---------------- prep2: swizzled 128x64 B-tiles for qkv (9 nb) + proj (3 nb) ----------------
__global__ void prep2(const float* __restrict__ qw, const float* __restrict__ pw,
                      short* __restrict__ wqb2, short* __restrict__ wpb) {
    int gt = blockIdx.x * 256 + threadIdx.x;    // 73728 total
    int tile = gt >> 10;
    int rem = gt & 1023;
    int r = rem >> 3, g = rem & 7;
    int kc = tile % 6;
    int k0 = kc * 64 + ((g ^ (r & 7)) << 3);
    short8 o;
    if (tile < 54) {
        int nb = tile / 6;
        const float* src = qw + (size_t)(nb * 128 + r) * DIMC + k0;
        #pragma unroll
        for (int e = 0; e < 8; ++e) o[e] = f2bf(src[e]);
        *(short8*)(wqb2 + (size_t)tile * 8192 + r * 64 + g * 8) = o;
    } else {
        int t2 = tile - 54;
        int nb = t2 / 6;
        const float* src = pw + (size_t)(nb * 128 + r) * DIMC + k0;
        #pragma unroll
        for (int e = 0; e < 8; ++e) o[e] = f2bf(src[e]);
        *(short8*)(wpb + (size_t)t2 * 8192 + r * 64 + g * 8) = o;
    }
}

// ---------------- prep_x: x -> bf16 pre-swizzled padded A-tiles (per chunk) ----------------
__global__ __launch_bounds__(1024)
void prep_x(const float* __restrict__ x, short* __restrict__ xa, int w0) {
    const int bid = blockIdx.x;
    const int mt = bid / 6, kc = bid % 6;
    const int tid = threadIdx.x;
    const int r = tid >> 3, g = tid & 7;
    const int win = w0 + mt * 2 + (r >> 6);
    const int tok = r & 63;
    const int k0 = kc * 64 + ((g ^ (r & 7)) << 3);
    short8 o;
    if (tok < NTOK) {
        const float* src = x + ((size_t)win * NTOK + tok) * DIMC + k0;
        float4 a = *(const float4*)src;
        float4 b = *(const float4*)(src + 4);
        o[0]=f2bf(a.x); o[1]=f2bf(a.y); o[2]=f2bf(a.z); o[3]=f2bf(a.w);
        o[4]=f2bf(b.x); o[5]=f2bf(b.y); o[6]=f2bf(b.z); o[7]=f2bf(b.w);
    } else {
        o = (short8)0;
    }
    *(short8*)(xa + ((size_t)mt * 6 + kc) * 8192 + r * 64 + g * 8) = o;
}

// ======= qkv_gemm: 128x128xK pipeline (A from xa, B from wqb2), frag-layout epilogue =======
__global__ __launch_bounds__(256, 2)
void qkv_gemm(const short* __restrict__ xa, const float* __restrict__ qkv_b,
              const short* __restrict__ wqb2, short* __restrict__ qkvb)
{
    __shared__ char LC[2][32768] __attribute__((aligned(128)));

    const int tid = threadIdx.x;
    const int wv = tid >> 6, lane = tid & 63;
    const int l15 = lane & 15, l4 = lane >> 4;
    const int wr = wv >> 1, wc = wv & 1;
    const int sg = blockIdx.x / 72, bb = blockIdx.x % 72;
    const int mb = sg * 8 + (bb & 7), nb = bb >> 3;

    const char* asrc = (const char*)xa + (size_t)mb * 6 * 16384;
    const char* bsrc = (const char*)wqb2 + (size_t)(nb * 6) * 8192 * 2;

    f32x4 acc[4][4];
    #pragma unroll
    for (int mi = 0; mi < 4; ++mi)
        #pragma unroll
        for (int ni = 0; ni < 4; ++ni) acc[mi][ni] = (f32x4){0.f, 0.f, 0.f, 0.f};

    #pragma unroll
    for (int it = 0; it < 4; ++it) {
        int L = (wv * 4 + it) * 1024;
        gld_lds16(asrc + L + lane * 16, &LC[0][L]);
        gld_lds16(bsrc + L + lane * 16, &LC[0][16384 + L]);
    }

    #pragma unroll
    for (int kc = 0; kc < 6; ++kc) {
        __builtin_amdgcn_sched_barrier(0);
        asm volatile("s_waitcnt vmcnt(0)" ::: "memory");
        __builtin_amdgcn_s_barrier();
        __builtin_amdgcn_sched_barrier(0);
        if (kc < 5) {
            #pragma unroll
            for (int it = 0; it < 4; ++it) {
                int L = (wv * 4 + it) * 1024;
                gld_lds16(asrc + (kc + 1) * 16384 + L + lane * 16, &LC[(kc + 1) & 1][L]);
                gld_lds16(bsrc + (kc + 1) * 16384 + L + lane * 16, &LC[(kc + 1) & 1][16384 + L]);
            }
        }
        const char* bufp = LC[kc & 1];
        __builtin_amdgcn_s_setprio(1);
        #pragma unroll
        for (int ksub = 0; ksub < 2; ++ksub) {
            short8 a[4], b[4];
            #pragma unroll
            for (int mi = 0; mi < 4; ++mi) {
                int row = wr * 64 + mi * 16 + l15;
                a[mi] = *(const short8*)(bufp + row * 128 +
                        ((ksub * 64 + l4 * 16) ^ ((row & 7) << 4)));
            }
            #pragma unroll
            for (int ni = 0; ni < 4; ++ni) {
                int row = wc * 64 + ni * 16 + l15;
                b[ni] = *(const short8*)(bufp + 16384 + row * 128 +
                        ((ksub * 64 + l4 * 16) ^ ((row & 7) << 4)));
            }
            #pragma unroll
            for (int mi = 0; mi < 4; ++mi)
                #pragma unroll
                for (int ni = 0; ni < 4; ++ni)
                    acc[mi][ni] = __builtin_amdgcn_mfma_f32_16x16x32_bf16(
                        a[mi], b[ni], acc[mi][ni], 0, 0, 0);
        }
        __builtin_amdgcn_s_setprio(0);
    }

    __syncthreads();   // all phases done before LC reuse as transpose slabs

    float bias[4];
    #pragma unroll
    for (int ni = 0; ni < 4; ++ni) bias[ni] = qkv_b[nb * 128 + wc * 64 + ni * 16 + l15];

    char* slab = (char*)LC + wv * 8192;   // 64 rows x 128B, wave-private
    const int wl = mb * 2 + wr;           // local window
    const int sub = nb / 3;               // 0=q 1=k 2=v

    if (sub < 2) {
        #pragma unroll
        for (int mi = 0; mi < 4; ++mi)
            #pragma unroll
            for (int ni = 0; ni < 4; ++ni)
                #pragma unroll
                for (int reg = 0; reg < 4; ++reg) {
                    float v = acc[mi][ni][reg] + bias[ni];
                    if (sub == 0) v *= QSCALE;
                    int rowp = mi * 16 + l4 * 4 + reg, colp = ni * 16 + l15;
                    *(short*)(slab + rowp * 128 + ((colp * 2) ^ ((rowp & 7) << 4))) = f2bf(v);
                }
        __builtin_amdgcn_sched_barrier(0);
        asm volatile("s_waitcnt lgkmcnt(0)" ::: "memory");
        __builtin_amdgcn_sched_barrier(0);
        #pragma unroll
        for (int hh = 0; hh < 2; ++hh)
            #pragma unroll
            for (int s = 0; s < 4; ++s) {
                int head = (nb % 3) * 4 + wc * 2 + hh;
                int rowp = s * 16 + l15;
                short8 frag = *(const short8*)(slab + rowp * 128 +
                              ((hh * 64 + l4 * 16) ^ ((rowp & 7) << 4)));
                *(short8*)(qkvb + (((size_t)wl * NH + head) * 12 + sub * 4 + s) * 512 + lane * 8) = frag;
            }
    } else {
        #pragma unroll
        for (int mi = 0; mi < 4; ++mi)
            #pragma unroll
            for (int ni = 0; ni < 4; ++ni)
                #pragma unroll
                for (int reg = 0; reg < 4; ++reg) {
                    float v = acc[mi][ni][reg] + bias[ni];
                    int rowp = mi * 16 + l4 * 4 + reg, colp = ni * 16 + l15;
                    *(short*)(slab + colp * 128 + ((rowp * 2) ^ ((colp & 7) << 4))) = f2bf(v);
                }
        __builtin_amdgcn_sched_barrier(0);
        asm volatile("s_waitcnt lgkmcnt(0)" ::: "memory");
        __builtin_amdgcn_sched_barrier(0);
        #pragma unroll
        for (int hh = 0; hh < 2; ++hh)
            #pragma unroll
            for (int dt = 0; dt < 2; ++dt)
                #pragma unroll
                for (int kst = 0; kst < 2; ++kst) {
                    int head = (nb - 6) * 4 + wc * 2 + hh;
                    int row2 = hh * 32 + dt * 16 + l15;
                    short8 frag = *(const short8*)(slab + row2 * 128 +
                                  ((kst * 64 + l4 * 16) ^ ((row2 & 7) << 4)));
                    *(short8*)(qkvb + (((size_t)wl * NH + head) * 12 + 8 + dt * 2 + kst) * 512 + lane * 8) = frag;
                }
    }
}

// ======= attnproj: 1 block = 1 window; attention -> AV in LDS -> proj -> out =======
// LDS (80 KB -> 2 blocks/CU): AVS [64 rows][768B swz] 49152 | BB 2x16384 (proj-only,
// shared region with attention-only PS 4x2048 + BT 4096)
#define AVS_OFF 0
#define BB_OFF  49152
#define PS_OFF2 49152
#define BT_OFF2 57344
#define APL_TOT 81920

__global__ __launch_bounds__(256)
void attnproj(const float* __restrict__ mask, const float* __restrict__ bias_table,
              const short* __restrict__ qkvb, const short* __restrict__ wpb,
              const float* __restrict__ proj_b, float* __restrict__ out, int w0)
{
    __shared__ char SB[APL_TOT] __attribute__((aligned(128)));
    short* BT = (short*)(SB + BT_OFF2);

    const int tid = threadIdx.x;
    const int wv = tid >> 6, lane = tid & 63;
    const int l15 = lane & 15, l4 = lane >> 4;
    const int st4 = wv;                 // q-stripe
    const int lw = blockIdx.x;          // local window in chunk
    const int win = w0 + lw;

    for (int i = tid; i < 169 * NH; i += 256) BT[i] = f2bf(bias_table[i]);

    // mask packed bf16 pairs (col-pad folded) + rel-idx, for stripe st4
    u32 mvp[4][2];
    int bidx[4][4];
    {
        const float* maskp = mask + (size_t)(win & 63) * (NTOK * NTOK);
        #pragma unroll
        for (int t = 0; t < 4; ++t) {
            int m = t * 16 + l15;
            float pad = (m < NTOK) ? 0.f : -1e30f;
            #pragma unroll
            for (int rp = 0; rp < 2; ++rp) {
                float v[2];
                #pragma unroll
                for (int e = 0; e < 2; ++e) {
                    int i = st4 * 16 + l4 * 4 + rp * 2 + e;
                    v[e] = ((i < NTOK && m < NTOK) ? maskp[i * NTOK + m] : 0.f) + pad;
                }
                mvp[t][rp] = (u32)(unsigned short)f2bf(v[0]) |
                             ((u32)(unsigned short)f2bf(v[1]) << 16);
            }
        }
        int cofi[4], cofm[4];
        #pragma unroll
        for (int t = 0; t < 4; ++t) {
            int m = t * 16 + l15;
            cofm[t] = cof(48 - (m < NTOK ? m : 48));
        }
        #pragma unroll
        for (int reg = 0; reg < 4; ++reg) {
            int i = st4 * 16 + l4 * 4 + reg;
            cofi[reg] = cof(i < NTOK ? i : 48);
        }
        #pragma unroll
        for (int t = 0; t < 4; ++t)
            #pragma unroll
            for (int reg = 0; reg < 4; ++reg)
                bidx[t][reg] = (cofi[reg] + cofm[t]) * NH;
    }
    const f32x4 zf = (f32x4){0.f, 0.f, 0.f, 0.f};
    __syncthreads();   // BT visible

    const short* qh = qkvb + (size_t)lw * (NH * 12 * 512);
    char* psw = SB + PS_OFF2 + wv * 2048;

    // ---------------- attention: 12 heads, zero block barriers ----------------
    #pragma unroll 1
    for (int h = 0; h < NH; ++h) {
        const short* hb = qh + h * (12 * 512) + lane * 8;
        short8 q = *(const short8*)(hb + st4 * 512);
        short8 kf[4], vf[4];
        #pragma unroll
        for (int t = 0; t < 4; ++t) kf[t] = *(const short8*)(hb + (4 + t) * 512);
        #pragma unroll
        for (int j = 0; j < 4; ++j) vf[j] = *(const short8*)(hb + (8 + j) * 512);

        f32x4 sc[4];
        #pragma unroll
        for (int t = 0; t < 4; ++t)
            sc[t] = __builtin_amdgcn_mfma_f32_16x16x32_bf16(q, kf[t], zf, 0, 0, 0);

        float p[4][4];
        #pragma unroll
        for (int t = 0; t < 4; ++t)
            #pragma unroll
            for (int reg = 0; reg < 4; ++reg) {
                u32 pk = mvp[t][reg >> 1];
                float mval = bf2f((short)((reg & 1) ? (pk >> 16) : (pk & 0xffff)));
                float bt = bf2f(BT[bidx[t][reg] + h]);
                p[t][reg] = sc[t][reg] + mval + bt;
            }
        #pragma unroll
        for (int reg = 0; reg < 4; ++reg) {
            float mx = fmaxf(fmaxf(p[0][reg], p[1][reg]), fmaxf(p[2][reg], p[3][reg]));
            #pragma unroll
            for (int off = 8; off >= 1; off >>= 1) mx = fmaxf(mx, __shfl_xor(mx, off, 64));
            float s0 = 0.f;
            #pragma unroll
            for (int t = 0; t < 4; ++t) { p[t][reg] = __expf(p[t][reg] - mx); s0 += p[t][reg]; }
            #pragma unroll
            for (int off = 8; off >= 1; off >>= 1) s0 += __shfl_xor(s0, off, 64);
            float rs = 1.f / s0;
            #pragma unroll
            for (int t = 0; t < 4; ++t) p[t][reg] *= rs;
        }
        // P -> per-wave slab (swizzled 128B rows)
        #pragma unroll
        for (int t = 0; t < 4; ++t)
            #pragma unroll
            for (int reg = 0; reg < 4; ++reg) {
                int r = l4 * 4 + reg;
                int byt = r * 128 + ((((t * 16 + l15) << 1)) ^ ((r & 7) << 4));
                *(short*)(psw + byt) = f2bf(p[t][reg]);
            }
        // PV
        f32x4 av[2];
        av[0] = zf; av[1] = zf;
        #pragma unroll
        for (int kst = 0; kst < 2; ++kst) {
            short8 pa;
            {
                int byt = l15 * 128 + (((kst * 64 + l4 * 16)) ^ ((l15 & 7) << 4));
                pa = *(const short8*)(psw + byt);
            }
            #pragma unroll
            for (int dt = 0; dt < 2; ++dt)
                av[dt] = __builtin_amdgcn_mfma_f32_16x16x32_bf16(pa, vf[dt * 2 + kst], av[dt], 0, 0, 0);
        }
        // AV -> AVS LDS (row = tok, col = h*32+d, swizzled like proj A-frags)
        #pragma unroll
        for (int dt = 0; dt < 2; ++dt)
            #pragma unroll
            for (int reg = 0; reg < 4; ++reg) {
                int tok = st4 * 16 + l4 * 4 + reg;
                if (tok < NTOK) {
                    int lb = (h * 32 + dt * 16 + l15) * 2;
                    *(short*)(SB + AVS_OFF + tok * 768 + (lb ^ ((tok & 7) << 4))) = f2bf(av[dt][reg]);
                }
            }
    }

    asm volatile("s_waitcnt lgkmcnt(0)" ::: "memory");
    __builtin_amdgcn_s_barrier();
    __builtin_amdgcn_sched_barrier(0);

    // ---------------- proj: out[64pad, 384] = AVS @ wpb^T + b ----------------
    const char* bsrc = (const char*)wpb;
    char* BB = SB + BB_OFF;

    // prologue: stage tile t=0 into buf 0 (overwrites PS/BT region — safe post-barrier)
    #pragma unroll
    for (int it = 0; it < 4; ++it) {
        int L = it * 4096 + wv * 1024;
        gld_lds16(bsrc + L + lane * 16, BB + L);
    }

    f32x4 acc[4][2];
    #pragma unroll
    for (int mi = 0; mi < 4; ++mi) { acc[mi][0] = zf; acc[mi][1] = zf; }

    #pragma unroll 1
    for (int t = 0; t < 18; ++t) {
        const int kc = t % 6, nb = t / 6;
        __builtin_amdgcn_sched_barrier(0);
        asm volatile("s_waitcnt vmcnt(0)" ::: "memory");
        __builtin_amdgcn_s_barrier();
        __builtin_amdgcn_sched_barrier(0);
        if (t < 17) {
            #pragma unroll
            for (int it = 0; it < 4; ++it) {
                int L = it * 4096 + wv * 1024;
                gld_lds16(bsrc + (size_t)(t + 1) * 16384 + L + lane * 16,
                          BB + ((t + 1) & 1) * 16384 + L);
            }
        }
        const char* bufp = BB + (t & 1) * 16384;
        __builtin_amdgcn_s_setprio(1);
        #pragma unroll
        for (int ksub = 0; ksub < 2; ++ksub) {
            short8 a[4], b[2];
            #pragma unroll
            for (int mi = 0; mi < 4; ++mi) {
                int row = mi * 16 + l15;
                a[mi] = *(const short8*)(SB + AVS_OFF + row * 768 +
                        ((kc * 128 + ksub * 64 + l4 * 16) ^ ((row & 7) << 4)));
            }
            #pragma unroll
            for (int ni = 0; ni < 2; ++ni) {
                int row = st4 * 32 + ni * 16 + l15;
                b[ni] = *(const short8*)(bufp + row * 128 +
                        ((ksub * 64 + l4 * 16) ^ ((row & 7) << 4)));
            }
            #pragma unroll
            for (int mi = 0; mi < 4; ++mi)
                #pragma unroll
                for (int ni = 0; ni < 2; ++ni)
                    acc[mi][ni] = __builtin_amdgcn_mfma_f32_16x16x32_bf16(
                        a[mi], b[ni], acc[mi][ni], 0, 0, 0);
        }
        __builtin_amdgcn_s_setprio(0);
        if (kc == 5) {
            #pragma unroll
            for (int ni = 0; ni < 2; ++ni) {
                const int col = nb * 128 + st4 * 32 + ni * 16 + l15;
                const float pb = proj_b[col];
                #pragma unroll
                for (int mi = 0; mi < 4; ++mi)
                    #pragma unroll
                    for (int reg = 0; reg < 4; ++reg) {
                        int tok = mi * 16 + l4 * 4 + reg;
                        if (tok < NTOK)
                            out[((size_t)win * NTOK + tok) * DIMC + col] = acc[mi][ni][reg] + pb;
                    }
            }
            #pragma unroll
            for (int mi = 0; mi < 4; ++mi) { acc[mi][0] = zf; acc[mi][1] = zf; }
        }
    }
}

// ================= fallback: monolithic gather kernel (no ws) =================
__global__ __launch_bounds__(256, 2)
void winattn_fallback(const float* __restrict__ x, const float* __restrict__ mask,
                      const float* __restrict__ qkv_w, const float* __restrict__ qkv_b,
                      const float* __restrict__ proj_w, const float* __restrict__ proj_b,
                      const float* __restrict__ bias_table, float* __restrict__ out)
{
    __shared__ short SL[26624] __attribute__((aligned(128)));
    const int tid = threadIdx.x, wv = tid >> 6, lane = tid & 63;
    const int l15 = lane & 15, l4 = lane >> 4;
    const int win = blockIdx.x;
    const int xbase = win * (NTOK * DIMC);
    const int KSo = 0, VTo = 2048, PSo = 4096, QAo = 8192;

    short8 xf[12];
    {
        const int row = wv * 16 + l15;
        const bool valid = row < NTOK;
        const float* xr = x + xbase + row * DIMC;
        #pragma unroll
        for (int ks = 0; ks < 12; ++ks)
            xf[ks] = valid ? gather_bf(xr, 0, ks * 32 + l4 * 8) : (short8)0;
    }
    float mv[4][4]; int bidx[4][4];
    {
        const float* maskp = mask + (win & 63) * (NTOK * NTOK);
        int cofi[4], cofm[4];
        float negm[4];
        #pragma unroll
        for (int t = 0; t < 4; ++t) {
            int m = t * 16 + l15;
            negm[t] = (m < NTOK) ? 0.f : -1e30f;
            cofm[t] = cof(48 - (m < NTOK ? m : 48));
            #pragma unroll
            for (int reg = 0; reg < 4; ++reg) {
                int i = wv * 16 + l4 * 4 + reg;
                mv[t][reg] = ((i < NTOK && m < NTOK) ? maskp[i * NTOK + m] : 0.f) + negm[t];
            }
        }
        #pragma unroll
        for (int reg = 0; reg < 4; ++reg) {
            int i = wv * 16 + l4 * 4 + reg;
            cofi[reg] = cof(i < NTOK ? i : 48);
        }
        #pragma unroll
        for (int t = 0; t < 4; ++t)
            #pragma unroll
            for (int reg = 0; reg < 4; ++reg) bidx[t][reg] = (cofi[reg] + cofm[t]) * NH;
    }
    f32x4 pacc[24];
    #pragma unroll
    for (int t = 0; t < 24; ++t) pacc[t] = (f32x4){0.f, 0.f, 0.f, 0.f};
    const f32x4 zf = (f32x4){0.f, 0.f, 0.f, 0.f};
    __syncthreads();

    #pragma unroll 1
    for (int h = 0; h < NH; ++h) {
        f32x4 qa[6];
        #pragma unroll
        for (int nt = 0; nt < 6; ++nt) qa[nt] = zf;
        #pragma unroll
        for (int nt = 0; nt < 6; ++nt) {
            const int grow = (nt >> 1) * DIMC + h * 32 + (nt & 1) * 16 + l15;
            #pragma unroll
            for (int ks = 0; ks < 12; ++ks) {
                short8 b = gather_bf(qkv_w, grow, ks * 32 + l4 * 8);
                qa[nt] = __builtin_amdgcn_mfma_f32_16x16x32_bf16(xf[ks], b, qa[nt], 0, 0, 0);
            }
        }
        #pragma unroll
        for (int nt = 0; nt < 6; ++nt) {
            const int sub = nt >> 1;
            const int colw = (nt & 1) * 16 + l15;
            const float bias = qkv_b[sub * DIMC + h * 32 + colw];
            #pragma unroll
            for (int reg = 0; reg < 4; ++reg) {
                const int tokg = wv * 16 + l4 * 4 + reg;
                float val = qa[nt][reg] + bias;
                if (sub == 0) {
                    int byt = tokg * 64 + ((colw << 1) ^ ((tokg & 3) << 4));
                    SL[QAo + (byt >> 1)] = f2bf(val * QSCALE);
                } else if (sub == 1) {
                    int byt = tokg * 64 + ((colw << 1) ^ ((tokg & 3) << 4));
                    SL[KSo + (byt >> 1)] = f2bf(val);
                } else {
                    int byt = colw * 128 + ((tokg << 1) ^ ((colw & 7) << 4));
                    SL[VTo + (byt >> 1)] = f2bf(val);
                }
            }
        }
        __syncthreads();
        short8 aq;
        { int row = wv*16+l15; int byt = row*64 + ((l4*16) ^ ((row&3)<<4));
          aq = *(const short8*)&SL[QAo + (byt>>1)]; }
        f32x4 sc[4];
        #pragma unroll
        for (int t = 0; t < 4; ++t) {
            int row = t*16+l15; int byt = row*64 + ((l4*16) ^ ((row&3)<<4));
            short8 bk = *(const short8*)&SL[KSo + (byt>>1)];
            sc[t] = __builtin_amdgcn_mfma_f32_16x16x32_bf16(aq, bk, zf, 0, 0, 0);
        }
        float p[4][4];
        #pragma unroll
        for (int t = 0; t < 4; ++t)
            #pragma unroll
            for (int reg = 0; reg < 4; ++reg)
                p[t][reg] = sc[t][reg] + mv[t][reg] + bias_table[bidx[t][reg] + h];
        #pragma unroll
        for (int reg = 0; reg < 4; ++reg) {
            float mx = fmaxf(fmaxf(p[0][reg], p[1][reg]), fmaxf(p[2][reg], p[3][reg]));
            #pragma unroll
            for (int off = 8; off >= 1; off >>= 1) mx = fmaxf(mx, __shfl_xor(mx, off, 64));
            float s0 = 0.f;
            #pragma unroll
            for (int t = 0; t < 4; ++t) { p[t][reg] = __expf(p[t][reg] - mx); s0 += p[t][reg]; }
            #pragma unroll
            for (int off = 8; off >= 1; off >>= 1) s0 += __shfl_xor(s0, off, 64);
            float rs = 1.f / s0;
            #pragma unroll
            for (int t = 0; t < 4; ++t) p[t][reg] *= rs;
        }
        #pragma unroll
        for (int t = 0; t < 4; ++t)
            #pragma unroll
            for (int reg = 0; reg < 4; ++reg) {
                int row = wv*16 + l4*4 + reg;
                int byt = row*128 + (((t*16+l15) << 1) ^ ((row&7)<<4));
                SL[PSo + (byt>>1)] = f2bf(p[t][reg]);
            }
        f32x4 av[2]; av[0] = zf; av[1] = zf;
        #pragma unroll
        for (int kst = 0; kst < 2; ++kst) {
            short8 pa;
            { int row = wv*16+l15; int byt = row*128 + ((kst*64+l4*16) ^ ((row&7)<<4));
              pa = *(const short8*)&SL[PSo + (byt>>1)]; }
            #pragma unroll
            for (int dt = 0; dt < 2; ++dt) {
                int d = dt*16+l15; int byt = d*128 + ((kst*64+l4*16) ^ ((d&7)<<4));
                short8 bv = *(const short8*)&SL[VTo + (byt>>1)];
                av[dt] = __builtin_amdgcn_mfma_f32_16x16x32_bf16(pa, bv, av[dt], 0, 0, 0);
            }
        }
        __syncthreads();
        #pragma unroll
        for (int dt = 0; dt < 2; ++dt)
            #pragma unroll
            for (int reg = 0; reg < 4; ++reg) {
                int row = wv*16 + l4*4 + reg;
                int byt = row*64 + (((dt*16+l15) << 1) ^ ((row&3)<<4));
                SL[QAo + (byt>>1)] = f2bf(av[dt][reg]);
            }
        __syncthreads();
        short8 aa;
        { int row = wv*16+l15; int byt = row*64 + ((l4*16) ^ ((row&3)<<4));
          aa = *(const short8*)&SL[QAo + (byt>>1)]; }
        #pragma unroll
        for (int nt = 0; nt < 24; ++nt) {
            short8 bp = gather_bf(proj_w, nt * 16 + l15, h * 32 + l4 * 8);
            pacc[nt] = __builtin_amdgcn_mfma_f32_16x16x32_bf16(aa, bp, pacc[nt], 0, 0, 0);
        }
    }
    {
        float* op = out + xbase;
        #pragma unroll
        for (int nt = 0; nt < 24; ++nt) {
            const float pb = proj_b[nt * 16 + l15];
            #pragma unroll
            for (int reg = 0; reg < 4; ++reg) {
                const int i = wv * 16 + l4 * 4 + reg;
                if (i < NTOK) op[i * DIMC + nt * 16 + l15] = pacc[nt][reg] + pb;
            }
        }
    }
}

extern "C" void kernel_launch(void* const* d_in, const int* in_sizes, int n_in,
                              void* d_out, int out_size, void* d_ws, size_t ws_size,
                              hipStream_t stream) {
    const float* x          = (const float*)d_in[0];
    const float* mask       = (const float*)d_in[1];
    const float* qkv_w      = (const float*)d_in[2];
    const float* qkv_b      = (const float*)d_in[3];
    const float* proj_w     = (const float*)d_in[4];
    const float* proj_b     = (const float*)d_in[5];
    const float* bias_table = (const float*)d_in[6];
    float* out = (float*)d_out;

    const size_t fixed = ((size_t)WQB2_SHORTS + WPB_SHORTS) * 2;
    auto need = [&](int c) {
        size_t wpc = 4096 / c;
        size_t mbc = wpc / 2;
        return fixed + mbc * 98304UL /*xa*/ + wpc * 147456UL /*qkvb*/;
    };
    int c = 0;
    if (ws_size >= need(4)) c = 4;
    else if (ws_size >= need(8)) c = 8;
    else if (ws_size >= need(16)) c = 16;

    if (c) {
        short* wqb2 = (short*)d_ws;
        short* wpb  = wqb2 + WQB2_SHORTS;
        const int wpc = 4096 / c;
        const int mbc = wpc / 2;
        short* xa   = wpb + WPB_SHORTS;
        short* qkvb = xa + (size_t)mbc * 49152;

        prep2<<<288, 256, 0, stream>>>(qkv_w, proj_w, wqb2, wpb);
        for (int ch = 0; ch < c; ++ch) {
            const int w0 = ch * wpc;
            prep_x<<<mbc * 6, 1024, 0, stream>>>(x, xa, w0);
            qkv_gemm<<<mbc * 9, 256, 0, stream>>>(xa, qkv_b, wqb2, qkvb);
            attnproj<<<wpc, 256, 0, stream>>>(mask, bias_table, qkvb, wpb, proj_b, out, w0);
        }
    } else {
        winattn_fallback<<<4096, 256, 0, stream>>>(x, mask, qkv_w, qkv_b, proj_w,
                                                   proj_b, bias_table, out);
    }
}